// Round 6
// baseline (322.208 us; speedup 1.0000x reference)
//
#include <hip/hip_runtime.h>
#include <hip/hip_bf16.h>
#include <math.h>

#define TT 365
#define BT 23360
#define NPOS 425

typedef __hip_bfloat16 bf16;
typedef __attribute__((ext_vector_type(8))) short s16x8;
typedef __attribute__((ext_vector_type(4))) float f32x4;

__device__ __forceinline__ float b2f(bf16 v) { return __bfloat162float(v); }
__device__ __forceinline__ bf16  f2b(float v) { return __float2bfloat16(v); }
__device__ __forceinline__ float u2f(unsigned u) { return __uint_as_float(u); }
__device__ __forceinline__ short f2bs(float v) { bf16 h = __float2bfloat16(v); return *reinterpret_cast<short*>(&h); }
__device__ __forceinline__ void unpack8(uint4 raw, float* v) {
    v[0] = u2f(raw.x << 16); v[1] = u2f(raw.x & 0xffff0000u);
    v[2] = u2f(raw.y << 16); v[3] = u2f(raw.y & 0xffff0000u);
    v[4] = u2f(raw.z << 16); v[5] = u2f(raw.z & 0xffff0000u);
    v[6] = u2f(raw.w << 16); v[7] = u2f(raw.w & 0xffff0000u);
}

// ---------------- prep: zero stats/pooled/esum, split-cast weights, pos table --------------------
// whi/wlo element offsets: w2@0(8192) w3@8192(32768) wi@40960(65536); total 106496
__global__ __launch_bounds__(256) void prep_kernel(
    float* __restrict__ stats, float* __restrict__ pooled, float* __restrict__ esum,
    const float* __restrict__ w2, const float* __restrict__ w3, const float* __restrict__ wi,
    bf16* __restrict__ whi, bf16* __restrict__ wlo, float* __restrict__ tab)
{
    int i = blockIdx.x * 256 + threadIdx.x;
    if (i < 2048)  { stats[i] = 0.f; return; }  i -= 2048;
    if (i < 16384) { pooled[i] = 0.f; return; } i -= 16384;
    if (i < 16384) { esum[i] = 0.f; return; }   i -= 16384;
    if (i < 106496) {
        float w;
        if      (i < 8192)   w = w2[i];
        else if (i < 40960)  w = w3[i - 8192];
        else                 w = wi[i - 40960];
        bf16 h = f2b(w);
        whi[i] = h;
        wlo[i] = f2b(w - b2f(h));
        return;
    } i -= 106496;
    if (i < 108800) {
        int c = i & 255, p = i >> 8;
        float e = (float)(2 * (c >> 1)) * (1.f / 256.f);
        float ang = (float)p * exp2f(-e * 9.96578428466209f);   // 1000^-e
        tab[i] = (c & 1) ? cosf(ang) : sinf(ang);
    }
}

// ---------------- L1 GEMM (K=10, f32 A): Y[M,64](bf16) = x @ w1^T + b1; fused BN stats ----------
__global__ __launch_bounds__(256) void gemm_l1_kernel(
    const float* __restrict__ x,
    const float* __restrict__ W, const float* __restrict__ bias,
    bf16* __restrict__ Y, float* __restrict__ stats)
{
    const int t  = threadIdx.x;
    const int tx = t & 15, ty = t >> 4;
    const int row0 = blockIdx.x * 64;
    __shared__ float As[64][17];
    __shared__ float Ws[16][65];
    __shared__ float red_s[4][64];
    __shared__ float red_q[4][64];
    float acc[4][4];
#pragma unroll
    for (int rr = 0; rr < 4; ++rr)
#pragma unroll
        for (int cc = 0; cc < 4; ++cc) acc[rr][cc] = 0.f;
#pragma unroll
    for (int i = 0; i < 4; ++i) {
        int idx = t + i * 256, r = idx >> 4, c = idx & 15;
        As[r][c] = (c < 10) ? x[(size_t)(row0 + r) * 10 + c] : 0.f;
    }
#pragma unroll
    for (int i = 0; i < 4; ++i) {
        int idx = t + i * 256, c = idx >> 4, kk = idx & 15;
        Ws[kk][c] = (kk < 10) ? W[(size_t)c * 10 + kk] : 0.f;
    }
    __syncthreads();
#pragma unroll
    for (int kk = 0; kk < 10; ++kk) {
        float a[4];
#pragma unroll
        for (int rr = 0; rr < 4; ++rr) a[rr] = As[ty * 4 + rr][kk];
#pragma unroll
        for (int cc = 0; cc < 4; ++cc) {
            float w = Ws[kk][cc * 16 + tx];
#pragma unroll
            for (int rr = 0; rr < 4; ++rr) acc[rr][cc] = fmaf(a[rr], w, acc[rr][cc]);
        }
    }
    float s_cc[4], q_cc[4];
#pragma unroll
    for (int cc = 0; cc < 4; ++cc) { s_cc[cc] = 0.f; q_cc[cc] = 0.f; }
#pragma unroll
    for (int rr = 0; rr < 4; ++rr) {
        int row = row0 + ty * 4 + rr;
#pragma unroll
        for (int cc = 0; cc < 4; ++cc) {
            int col = cc * 16 + tx;
            float v = acc[rr][cc] + bias[col];
            Y[(size_t)row * 64 + col] = f2b(v);
            s_cc[cc] += v; q_cc[cc] += v * v;
        }
    }
    int w = t >> 6;
#pragma unroll
    for (int cc = 0; cc < 4; ++cc) {
        float s = s_cc[cc], q = q_cc[cc];
        s += __shfl_xor(s, 16); q += __shfl_xor(q, 16);
        s += __shfl_xor(s, 32); q += __shfl_xor(q, 32);
        if ((t & 63) < 16) { red_s[w][cc * 16 + tx] = s; red_q[w][cc * 16 + tx] = q; }
    }
    __syncthreads();
    if (t < 64) {
        float s = red_s[0][t] + red_s[1][t] + red_s[2][t] + red_s[3][t];
        float q = red_q[0][t] + red_q[1][t] + red_q[2][t] + red_q[3][t];
        atomicAdd(&stats[t], s);
        atomicAdd(&stats[256 + t], q);
    }
}

// ---------------- MFMA GEMM, LDS-staged W, A prefetched to registers ----------------
// MODE 1: A = relu(bn(y)). MODE 2: A = relu(bn(y)) + se[b,k].
// Epilogue v2: output routed through an LDS tile (reuses Wl) and stored as full
// 128B-line writes (8 lanes x 16B per row) -- kills L2 write-allocate RMW that
// showed as +12MB FETCH_SIZE and 850 GB/s effective BW.
template<int MODE, int K>
__global__ __launch_bounds__(256) void mfma_gemm(
    const bf16* __restrict__ A,
    const bf16* __restrict__ Whi, const bf16* __restrict__ Wlo,
    const float* __restrict__ bias,
    bf16* __restrict__ Y, int ldY, float* __restrict__ stats,
    const float* __restrict__ bnstats, const float* __restrict__ bng,
    const float* __restrict__ bnb, const float* __restrict__ sebuf)
{
    constexpr int KC = (K > 128) ? 128 : K;      // staged chunk
    __shared__ s16x8 Wl[2][KC / 8][64];          // [hi/lo][kgroup][col]; reused as out-tile
    __shared__ float red_s[4][64];
    __shared__ float red_q[4][64];
    __shared__ float scb[MODE ? K : 1];
    __shared__ float shb[MODE ? K : 1];
    const int t = threadIdx.x, wave = t >> 6, lane = t & 63;
    const int n16 = lane & 15, quad = lane >> 4;
    const int m0 = blockIdx.x * 64 + wave * 16;
    const int col0 = blockIdx.y * 64;
    const int sc_ = t & 63, skg0 = t >> 6;       // staging roles
    const bf16* gh = Whi + (size_t)(col0 + sc_) * K;
    const bf16* gl = Wlo + (size_t)(col0 + sc_) * K;
    // stage chunk 0 + BN coeffs
#pragma unroll
    for (int kg = skg0; kg < KC / 8; kg += 4) {
        Wl[0][kg][sc_] = *(const s16x8*)(gh + kg * 8);
        Wl[1][kg][sc_] = *(const s16x8*)(gl + kg * 8);
    }
    if (MODE) {
        if (t < K) {
            float mu = bnstats[t] * (1.f / (float)BT);
            float var = bnstats[256 + t] * (1.f / (float)BT) - mu * mu;
            float sc = rsqrtf(var + 1e-5f) * bng[t];
            scb[t] = sc; shb[t] = bnb[t] - mu * sc;
        }
    }
    __syncthreads();
    // prefetch + transform all A fragments
    const int arow = m0 + n16;
    const float* sev = (MODE == 2) ? (sebuf + (arow / TT) * 256) : nullptr;
    const bf16* Ap = A + (size_t)arow * K + quad * 8;
    s16x8 af[K / 32];
#pragma unroll
    for (int i = 0; i < K / 32; ++i) {
        s16x8 raw = *(const s16x8*)(Ap + i * 32);
        if (MODE) {
            int kb = i * 32 + quad * 8;
#pragma unroll
            for (int j = 0; j < 8; ++j) {
                float y = u2f(((unsigned)(unsigned short)raw[j]) << 16);
                float v = fmaxf(fmaf(y, scb[kb + j], shb[kb + j]), 0.f);
                if (MODE == 2) v += sev[kb + j];
                raw[j] = f2bs(v);
            }
        }
        af[i] = raw;
    }
    f32x4 acc[4];
    f32x4 zero = {0.f, 0.f, 0.f, 0.f};
#pragma unroll
    for (int ct = 0; ct < 4; ++ct) acc[ct] = zero;
    // K loop over staged chunks
#pragma unroll
    for (int kc = 0; kc < K; kc += KC) {
        if (kc) {
            __syncthreads();   // all waves done with previous chunk
#pragma unroll
            for (int kg = skg0; kg < KC / 8; kg += 4) {
                Wl[0][kg][sc_] = *(const s16x8*)(gh + kc + kg * 8);
                Wl[1][kg][sc_] = *(const s16x8*)(gl + kc + kg * 8);
            }
            __syncthreads();
        }
#pragma unroll
        for (int i = 0; i < KC / 32; ++i) {
            const int kgq = i * 4 + quad;
            const s16x8 a = af[(kc >> 5) + i];
#pragma unroll
            for (int ct = 0; ct < 4; ++ct) {
                s16x8 bl = Wl[1][kgq][ct * 16 + n16];
                s16x8 bh = Wl[0][kgq][ct * 16 + n16];
                acc[ct] = __builtin_amdgcn_mfma_f32_16x16x32_bf16(a, bl, acc[ct], 0, 0, 0);
                acc[ct] = __builtin_amdgcn_mfma_f32_16x16x32_bf16(a, bh, acc[ct], 0, 0, 0);
            }
        }
    }
    // ---- epilogue v2: bias + BN-stats (unchanged math), output via LDS tile ----
    __syncthreads();                       // all waves done reading Wl
    bf16* tile = (bf16*)Wl;                // [wave][16 rows][72 shorts] (144B row stride)
#pragma unroll
    for (int ct = 0; ct < 4; ++ct) {
        int col = col0 + ct * 16 + n16;
        float bv = bias[col];
        float s = 0.f, q = 0.f;
#pragma unroll
        for (int r = 0; r < 4; ++r) {
            float v = acc[ct][r] + bv;
            tile[wave * 1152 + (quad * 4 + r) * 72 + ct * 16 + n16] = f2b(v);
            s += v; q += v * v;
        }
        s += __shfl_xor(s, 16); q += __shfl_xor(q, 16);
        s += __shfl_xor(s, 32); q += __shfl_xor(q, 32);
        if (quad == 0) { red_s[wave][ct * 16 + n16] = s; red_q[wave][ct * 16 + n16] = q; }
    }
    __syncthreads();
    // full-line stores: pass p covers rows p*32 + (t>>3); thread stores 16B (8 cols)
    const int rowbase = blockIdx.x * 64;
#pragma unroll
    for (int p = 0; p < 2; ++p) {
        int row = p * 32 + (t >> 3);
        int wv = row >> 4, rr = row & 15;
        s16x8 val = *(const s16x8*)&tile[wv * 1152 + rr * 72 + (t & 7) * 8];
        *(s16x8*)(Y + (size_t)(rowbase + row) * ldY + col0 + (t & 7) * 8) = val;
    }
    if (stats) {
        if (t < 64) {
            float s = red_s[0][t] + red_s[1][t] + red_s[2][t] + red_s[3][t];
            float q = red_q[0][t] + red_q[1][t] + red_q[2][t] + red_q[3][t];
            atomicAdd(&stats[col0 + t], s);
            atomicAdd(&stats[256 + col0 + t], q);
        }
    }
}

// ---------------- pool partial: pooled[b,f] += sum_rows relu(bn3(Y3)) ----------------
__global__ __launch_bounds__(256) void pool_partial_kernel(
    const bf16* __restrict__ Y3, const float* __restrict__ stats,
    const float* __restrict__ g3, const float* __restrict__ e3,
    float* __restrict__ pooled)
{
    const int b = blockIdx.x, part = blockIdx.y, t = threadIdx.x;
    const int cg = t & 31, rs = t >> 5;
    __shared__ float scb[256], shb[256];
    __shared__ float pp[8][256];
    {
        float mu = stats[t] * (1.f / (float)BT);
        float var = stats[256 + t] * (1.f / (float)BT) - mu * mu;
        float sc = rsqrtf(var + 1e-5f) * g3[t];
        scb[t] = sc; shb[t] = e3[t] - mu * sc;
    }
    __syncthreads();
    float acc[8] = {0.f,0.f,0.f,0.f,0.f,0.f,0.f,0.f};
    const int r0 = part * 46;
#pragma unroll
    for (int i = 0; i < 6; ++i) {
        int l = rs + i * 8;
        int r = r0 + l;
        if (l < 46 && r < TT) {
            uint4 raw = *(const uint4*)(Y3 + ((size_t)b * TT + r) * 256 + cg * 8);
            float v[8];
            unpack8(raw, v);
#pragma unroll
            for (int j = 0; j < 8; ++j)
                acc[j] += fmaxf(fmaf(v[j], scb[cg * 8 + j], shb[cg * 8 + j]), 0.f);
        }
    }
#pragma unroll
    for (int j = 0; j < 8; ++j) pp[rs][cg * 8 + j] = acc[j];
    __syncthreads();
    float s = 0.f;
#pragma unroll
    for (int r = 0; r < 8; ++r) s += pp[r][t];
    atomicAdd(&pooled[b * 256 + t], s);
}

// ---------------- SE MLP ----------------
__global__ __launch_bounds__(256) void se_mlp_kernel(const float* __restrict__ pooled,
                                                     const float* __restrict__ ws1,
                                                     const float* __restrict__ ws2,
                                                     float* __restrict__ se) {
    int b = blockIdx.x, f = threadIdx.x;
    __shared__ float pl[256];
    __shared__ float hidden[16];
    float p = pooled[b * 256 + f] * (1.f / (float)TT);
    pl[f] = p;
    __syncthreads();
    if (f < 16) {
        float h = 0.f;
        for (int k2 = 0; k2 < 256; ++k2) h = fmaf(pl[k2], ws1[f * 256 + k2], h);
        hidden[f] = fmaxf(h, 0.f);
    }
    __syncthreads();
    float a = 0.f;
    for (int k2 = 0; k2 < 16; ++k2) a = fmaf(hidden[k2], ws2[f * 16 + k2], a);
    a = 1.f / (1.f + expf(-a));
    se[b * 256 + f] = a * p;
}

// ---------------- BN + ReLU + positional add + fused esum column sums ----------------
__global__ __launch_bounds__(256) void bnrelu8_kernel(
    const bf16* __restrict__ Y, const float* __restrict__ stats,
    const float* __restrict__ g, const float* __restrict__ beta,
    bf16* __restrict__ Out, const float* __restrict__ tab, const int* __restrict__ pos,
    float* __restrict__ esum) {
    __shared__ float pe[8][256];
    const int t = threadIdx.x;
    int i = (blockIdx.x * 256 + t) * 8;
    int col = i & 255, row = i >> 8;
    uint4 raw = *(const uint4*)(Y + i);
    float v[8];
    unpack8(raw, v);
    const float invM = 1.f / (float)BT;
    const float* tr = tab + pos[row] * 256 + col;
    bf16 tmp[8] __attribute__((aligned(16)));
    float* pr = &pe[t >> 5][col];
#pragma unroll
    for (int j = 0; j < 8; ++j) {
        float mu  = stats[col + j] * invM;
        float var = stats[256 + col + j] * invM - mu * mu;
        float o = (v[j] - mu) * rsqrtf(var + 1e-5f) * g[col + j] + beta[col + j];
        float ev = fmaxf(o, 0.f) + tr[j];
        tmp[j] = f2b(ev);
        pr[j] = ev;
    }
    *(uint4*)(Out + i) = *(const uint4*)tmp;
    __syncthreads();
    const int g0 = blockIdx.x * 8;          // global row of block-row 0
    const int b0 = g0 / TT, b1 = (g0 + 7) / TT;
    const int split = (b1 != b0) ? (b1 * TT - g0) : 8;
    float s0 = 0.f, s1 = 0.f;
#pragma unroll
    for (int rr = 0; rr < 8; ++rr) {
        float vv = pe[rr][t];
        if (rr < split) s0 += vv; else s1 += vv;
    }
    atomicAdd(&esum[b0 * 256 + t], s0);
    if (b1 != b0) atomicAdd(&esum[b1 * 256 + t], s1);
}

// ---------------- attention v3: one wave per (b,h); q-projection fused away ----------------
__global__ __launch_bounds__(64) void attn3_kernel(
    const bf16* __restrict__ e, const float* __restrict__ esum,
    const float* __restrict__ wk, const float* __restrict__ bk,
    const float* __restrict__ wq, const float* __restrict__ bq,
    float* __restrict__ yv)
{
    __shared__ float kqL[256];
    __shared__ float aw[368];
    const int b = blockIdx.x, h = blockIdx.y;
    const int lane = threadIdx.x;
    // ks[8] from esum (lane covers cols lane*4..+4)
    float4 es = *(const float4*)(esum + b * 256 + lane * 4);
    float ks[8];
#pragma unroll
    for (int d = 0; d < 8; ++d) {
        float4 wv = *(const float4*)(wk + (size_t)(h * 8 + d) * 256 + lane * 4);
        ks[d] = es.x * wv.x + es.y * wv.y + es.z * wv.z + es.w * wv.w;
    }
#pragma unroll
    for (int off = 1; off < 64; off <<= 1)
#pragma unroll
        for (int d = 0; d < 8; ++d) ks[d] += __shfl_xor(ks[d], off);
#pragma unroll
    for (int d = 0; d < 8; ++d) ks[d] += (float)TT * bk[h * 8 + d];
    // kq for my 4 cols; cb = bq_h . ks (same on all lanes)
    {
        float4 kq = {0.f, 0.f, 0.f, 0.f};
#pragma unroll
        for (int d = 0; d < 8; ++d) {
            float4 wv = *(const float4*)(wq + (size_t)(h * 8 + d) * 256 + lane * 4);
            kq.x = fmaf(ks[d], wv.x, kq.x);
            kq.y = fmaf(ks[d], wv.y, kq.y);
            kq.z = fmaf(ks[d], wv.z, kq.z);
            kq.w = fmaf(ks[d], wv.w, kq.w);
        }
        *(float4*)&kqL[lane * 4] = kq;
    }
    float cb = 0.f;
#pragma unroll
    for (int d = 0; d < 8; ++d) cb = fmaf(ks[d], bq[h * 8 + d], cb);
    __syncthreads();
    // scores: 8 groups of 8 lanes; group g handles rows r = it*8+g; lane covers 32 cols
    const int gp = lane >> 3, gl = lane & 7;
    float4 kr[8];
    {
        const float4* kq4 = (const float4*)(kqL + gl * 32);
#pragma unroll
        for (int u = 0; u < 8; ++u) kr[u] = kq4[u];
    }
    const float scale = 1.f / (sqrtf(8.f) * (float)TT);
    const bf16* ebs = e + (size_t)b * TT * 256 + gl * 32;
    for (int it = 0; it < 46; ++it) {
        int r = it * 8 + gp;
        if (r < TT) {
            const bf16* ep = ebs + (size_t)r * 256;
            float dot = 0.f;
#pragma unroll
            for (int u = 0; u < 4; ++u) {
                uint4 raw = *(const uint4*)(ep + u * 8);
                float v[8];
                unpack8(raw, v);
                float4 ka = kr[u * 2], kb2 = kr[u * 2 + 1];
                dot += v[0] * ka.x + v[1] * ka.y + v[2] * ka.z + v[3] * ka.w
                     + v[4] * kb2.x + v[5] * kb2.y + v[6] * kb2.z + v[7] * kb2.w;
            }
            dot += __shfl_xor(dot, 1);
            dot += __shfl_xor(dot, 2);
            dot += __shfl_xor(dot, 4);
            if (gl == 0) aw[r] = (dot + cb) * scale;
        }
    }
    __syncthreads();
    // softmax over rows (lane covers 6 rows)
    float sv[6];
    float m = -1e30f;
#pragma unroll
    for (int i = 0; i < 6; ++i) {
        int r = lane + i * 64;
        sv[i] = (r < TT) ? aw[r] : -1e30f;
        m = fmaxf(m, sv[i]);
    }
#pragma unroll
    for (int off = 1; off < 64; off <<= 1) m = fmaxf(m, __shfl_xor(m, off));
    float sum = 0.f;
#pragma unroll
    for (int i = 0; i < 6; ++i) {
        float ev = (sv[i] > -1e29f) ? expf(sv[i] - m) : 0.f;
        sv[i] = ev; sum += ev;
    }
#pragma unroll
    for (int off = 1; off < 64; off <<= 1) sum += __shfl_xor(sum, off);
    float inv = 1.f / sum;
#pragma unroll
    for (int i = 0; i < 6; ++i) {
        int r = lane + i * 64;
        if (r < TT) aw[r] = sv[i] * inv;
    }
    __syncthreads();
    // yv[b, h*16 + half*8 + j] = sum_r aw[r] * e[b,r,col]
    const int half = lane & 1, rs = lane >> 1;
    float acc[8] = {0.f,0.f,0.f,0.f,0.f,0.f,0.f,0.f};
    const bf16* ebase = e + (size_t)b * TT * 256 + h * 16 + half * 8;
#pragma unroll
    for (int i = 0; i < 12; ++i) {
        int r = rs + i * 32;
        if (r < TT) {
            uint4 raw = *(const uint4*)(ebase + (size_t)r * 256);
            float v[8];
            unpack8(raw, v);
            float a = aw[r];
#pragma unroll
            for (int j = 0; j < 8; ++j) acc[j] = fmaf(a, v[j], acc[j]);
        }
    }
#pragma unroll
    for (int off = 2; off < 64; off <<= 1)
#pragma unroll
        for (int j = 0; j < 8; ++j) acc[j] += __shfl_xor(acc[j], off);
    if (lane < 2) {
        float* op = yv + b * 256 + h * 16 + half * 8;
#pragma unroll
        for (int j = 0; j < 8; ++j) op[j] = acc[j];
    }
}

// ---------------- tail v4: column-parallel split of the PROVEN v2 tail ----------------

// layer m: 256 -> 128. grid 16; wave cw handles cols c0=bx*8+cw*2, c0+1.
__global__ __launch_bounds__(256) void tail_m_kernel(
    const float* __restrict__ yv, const float* __restrict__ wm,
    const float* __restrict__ gm, const float* __restrict__ em,
    float* __restrict__ z1)
{
    __shared__ float Xq[4160];           // [64k][65]
    const int t = threadIdx.x, r = t & 63, cw = t >> 6;
    const int c0 = blockIdx.x * 8 + cw * 2;
    const float4* wf4 = (const float4*)wm;   // [128][64 float4]
    float acc[2] = {0.f, 0.f};
    for (int p = 0; p < 4; ++p) {
        if (p) __syncthreads();
        for (int i = t; i < 4096; i += 256) {
            int kk = i & 63, rr = i >> 6;
            Xq[kk * 65 + rr] = yv[rr * 256 + p * 64 + kk];
        }
        __syncthreads();
#pragma unroll 4
        for (int k4 = 0; k4 < 16; ++k4) {
            float xv[4];
#pragma unroll
            for (int j = 0; j < 4; ++j) xv[j] = Xq[(k4 * 4 + j) * 65 + r];
#pragma unroll
            for (int c = 0; c < 2; ++c) {
                float4 w = wf4[(c0 + c) * 64 + p * 16 + k4];
                acc[c] = fmaf(xv[0], w.x, acc[c]);
                acc[c] = fmaf(xv[1], w.y, acc[c]);
                acc[c] = fmaf(xv[2], w.z, acc[c]);
                acc[c] = fmaf(xv[3], w.w, acc[c]);
            }
        }
    }
#pragma unroll
    for (int c = 0; c < 2; ++c) {
        float v = acc[c];
        float s = v, q = v * v;
#pragma unroll
        for (int off = 1; off < 64; off <<= 1) { s += __shfl_xor(s, off); q += __shfl_xor(q, off); }
        float mu = s * (1.f / 64.f), var = q * (1.f / 64.f) - mu * mu;
        float sc = rsqrtf(var + 1e-5f) * gm[c0 + c], sh = em[c0 + c] - mu * sc;
        z1[r * 128 + c0 + c] = fmaxf(fmaf(v, sc, sh), 0.f);
    }
}

// layer d1: 128 -> 64. grid 8; wave cw handles cols c0=bx*8+cw*2, c0+1.
__global__ __launch_bounds__(256) void tail_d1_kernel(
    const float* __restrict__ z1, const float* __restrict__ wd1,
    const float* __restrict__ gd1, const float* __restrict__ ed1,
    float* __restrict__ z2)
{
    __shared__ float Xq[4160];
    const int t = threadIdx.x, r = t & 63, cw = t >> 6;
    const int c0 = blockIdx.x * 8 + cw * 2;
    const float4* wf4 = (const float4*)wd1;  // [64][32 float4]
    float acc[2] = {0.f, 0.f};
    for (int p = 0; p < 2; ++p) {
        if (p) __syncthreads();
        for (int i = t; i < 4096; i += 256) {
            int kk = i & 63, rr = i >> 6;
            Xq[kk * 65 + rr] = z1[rr * 128 + p * 64 + kk];
        }
        __syncthreads();
#pragma unroll 4
        for (int k4 = 0; k4 < 16; ++k4) {
            float xv[4];
#pragma unroll
            for (int j = 0; j < 4; ++j) xv[j] = Xq[(k4 * 4 + j) * 65 + r];
#pragma unroll
            for (int c = 0; c < 2; ++c) {
                float4 w = wf4[(c0 + c) * 32 + p * 16 + k4];
                acc[c] = fmaf(xv[0], w.x, acc[c]);
                acc[c] = fmaf(xv[1], w.y, acc[c]);
                acc[c] = fmaf(xv[2], w.z, acc[c]);
                acc[c] = fmaf(xv[3], w.w, acc[c]);
            }
        }
    }
#pragma unroll
    for (int c = 0; c < 2; ++c) {
        float v = acc[c];
        float s = v, q = v * v;
#pragma unroll
        for (int off = 1; off < 64; off <<= 1) { s += __shfl_xor(s, off); q += __shfl_xor(q, off); }
        float mu = s * (1.f / 64.f), var = q * (1.f / 64.f) - mu * mu;
        float sc = rsqrtf(var + 1e-5f) * gd1[c0 + c], sh = ed1[c0 + c] - mu * sc;
        z2[r * 64 + c0 + c] = fmaxf(fmaf(v, sc, sh), 0.f);
    }
}

// layer d2 (64 -> 32) + classifier (32 -> 10). 1 block x 256thr; wave cw = 8 cols.
__global__ __launch_bounds__(256) void tail_d2c_kernel(
    const float* __restrict__ z2, const float* __restrict__ wd2,
    const float* __restrict__ gd2, const float* __restrict__ ed2,
    const float* __restrict__ wc, const float* __restrict__ bc,
    float* __restrict__ out)
{
    __shared__ float Xq[4160];           // [64k][65]
    __shared__ float Z3t[2048];          // [32][64]
    __shared__ float WcL[320];           // [10][32]
    const int t = threadIdx.x, r = t & 63, cw = t >> 6;
    const int c03 = cw * 8;
    for (int i = t; i < 4096; i += 256) {
        int kk = i & 63, rr = i >> 6;
        Xq[kk * 65 + rr] = z2[rr * 64 + kk];
    }
    if (t < 80) ((float4*)WcL)[t] = ((const float4*)wc)[t];
    __syncthreads();
    const float4* wf4 = (const float4*)wd2;  // [32][16 float4]
    float acc[8] = {0.f,0.f,0.f,0.f,0.f,0.f,0.f,0.f};
#pragma unroll 4
    for (int k4 = 0; k4 < 16; ++k4) {
        float xv[4];
#pragma unroll
        for (int j = 0; j < 4; ++j) xv[j] = Xq[(k4 * 4 + j) * 65 + r];
#pragma unroll
        for (int c = 0; c < 8; ++c) {
            float4 w = wf4[(c03 + c) * 16 + k4];
            acc[c] = fmaf(xv[0], w.x, acc[c]);
            acc[c] = fmaf(xv[1], w.y, acc[c]);
            acc[c] = fmaf(xv[2], w.z, acc[c]);
            acc[c] = fmaf(xv[3], w.w, acc[c]);
        }
    }
#pragma unroll
    for (int c = 0; c < 8; ++c) {
        float v = acc[c];
        float s = v, q = v * v;
#pragma unroll
        for (int off = 1; off < 64; off <<= 1) { s += __shfl_xor(s, off); q += __shfl_xor(q, off); }
        float mu = s * (1.f / 64.f), var = q * (1.f / 64.f) - mu * mu;
        float sc = rsqrtf(var + 1e-5f) * gd2[c03 + c], sh = ed2[c03 + c] - mu * sc;
        Z3t[(c03 + c) * 64 + r] = fmaxf(fmaf(v, sc, sh), 0.f);
    }
    __syncthreads();
#pragma unroll
    for (int i = 0; i < 3; ++i) {
        int idx = t + i * 256;
        if (idx < 640) {
            int rr = idx / 10, c = idx - rr * 10;
            float s = bc[c];
#pragma unroll
            for (int kk = 0; kk < 32; ++kk) s = fmaf(Z3t[kk * 64 + rr], WcL[c * 32 + kk], s);
            out[idx] = s;
        }
    }
}

// ---------------- launch ----------------

extern "C" void kernel_launch(void* const* d_in, const int* in_sizes, int n_in,
                              void* d_out, int out_size, void* d_ws, size_t ws_size,
                              hipStream_t stream) {
    (void)in_sizes; (void)n_in; (void)out_size; (void)ws_size;
    const float* x  = (const float*)d_in[0];
    const int* pos  = (const int*)d_in[1];
    const float *w1 = (const float*)d_in[2],  *b1 = (const float*)d_in[3],
                *g1 = (const float*)d_in[4],  *e1 = (const float*)d_in[5];
    const float *w2 = (const float*)d_in[6],  *b2 = (const float*)d_in[7],
                *g2 = (const float*)d_in[8],  *e2 = (const float*)d_in[9];
    const float *w3 = (const float*)d_in[10], *b3 = (const float*)d_in[11],
                *g3 = (const float*)d_in[12], *e3 = (const float*)d_in[13];
    const float *ws1 = (const float*)d_in[14], *ws2 = (const float*)d_in[15];
    const float *wi = (const float*)d_in[16], *bi = (const float*)d_in[17],
                *gi = (const float*)d_in[18], *ei = (const float*)d_in[19];
    const float *wk = (const float*)d_in[20], *bk = (const float*)d_in[21];   // k before q!
    const float *wq = (const float*)d_in[22], *bq = (const float*)d_in[23];
    const float *wm = (const float*)d_in[24], *bm = (const float*)d_in[25],
                *gm = (const float*)d_in[26], *em = (const float*)d_in[27];
    const float *wd1 = (const float*)d_in[28], *bd1 = (const float*)d_in[29],
                *gd1 = (const float*)d_in[30], *ed1 = (const float*)d_in[31];
    const float *wd2 = (const float*)d_in[32], *bd2 = (const float*)d_in[33],
                *gd2 = (const float*)d_in[34], *ed2 = (const float*)d_in[35];
    const float *wc = (const float*)d_in[36], *bc = (const float*)d_in[37];
    float* out = (float*)d_out;
    (void)bm; (void)bd1; (void)bd2;   // linear biases cancel under train-mode BN

    char* w8 = (char*)d_ws;
    bf16*  actA   = (bf16*)(w8);                    // 11,960,320
    bf16*  actB   = (bf16*)(w8 + 11960320);         // 11,960,320
    bf16*  whi    = (bf16*)(w8 + 23920640);         //    278,528
    bf16*  wlo    = (bf16*)(w8 + 24199168);         //    278,528
    float* tab    = (float*)(w8 + 24477696);        //    435,200
    float* stats  = (float*)(w8 + 24912896);        //      8,192
    float* pooled = (float*)(w8 + 24921088);        //     65,536
    float* sebuf  = (float*)(w8 + 24986624);        //     65,536
    float* esum   = (float*)(w8 + 25052160);        //     65,536
    float* yvb    = (float*)(w8 + 25117696);        //     65,536
    // tail intermediates reuse regions that are dead after attn (rewritten by prep each launch)
    float* z1     = esum;        // 32,768 of 65,536 (esum last read by attn3)
    float* z2     = sebuf;       // 16,384 of 65,536 (sebuf last read by inconv gemm)

    prep_kernel<<<977, 256, 0, stream>>>(stats, pooled, esum, w2, w3, wi, whi, wlo, tab);
    // L1: 10 -> 64 -> Y1 = actB + stats1
    gemm_l1_kernel<<<365, 256, 0, stream>>>(x, w1, b1, actB, stats);
    // L2: 64 -> 128, fused BN1 -> Y2 = actA + stats2
    mfma_gemm<1, 64><<<dim3(365, 2), 256, 0, stream>>>(actB, whi, wlo, b2,
                                                       actA, 128, stats + 512, stats, g1, e1, nullptr);
    // L3: 128 -> 256, fused BN2 -> Y3 = actB + stats3
    mfma_gemm<1, 128><<<dim3(365, 4), 256, 0, stream>>>(actA, whi + 8192, wlo + 8192, b3,
                                                        actB, 256, stats + 1024, stats + 512, g2, e2, nullptr);
    // pool (fused BN3+relu) -> pooled; SE MLP -> sebuf
    pool_partial_kernel<<<dim3(64, 8), 256, 0, stream>>>(actB, stats + 1024, g3, e3, pooled);
    se_mlp_kernel<<<64, 256, 0, stream>>>(pooled, ws1, ws2, sebuf);
    // inconv: A = Y3 with fused BN3+relu+SE-residual -> Yi = actA + statsi
    mfma_gemm<2, 256><<<dim3(365, 4), 256, 0, stream>>>(actB, whi + 40960, wlo + 40960, bi,
                                                        actA, 256, stats + 1536, stats + 1024, g3, e3, sebuf);
    // bn_i + relu + PE -> e = actB; esum fused
    bnrelu8_kernel<<<BT * 256 / 2048, 256, 0, stream>>>(actA, stats + 1536, gi, ei, actB, tab, pos, esum);
    // attention v3: q GEMM fused away via kq = wq^T.ks
    attn3_kernel<<<dim3(64, 16), 64, 0, stream>>>(actB, esum, wk, bk, wq, bq, yvb);
    // tail v4: column-parallel, v2-proven building blocks
    tail_m_kernel<<<16, 256, 0, stream>>>(yvb, wm, gm, em, z1);
    tail_d1_kernel<<<8, 256, 0, stream>>>(z1, wd1, gd1, ed1, z2);
    tail_d2c_kernel<<<1, 256, 0, stream>>>(z2, wd2, gd2, ed2, wc, bc, out);
}

// Round 7
// 295.647 us; speedup vs baseline: 1.0898x; 1.0898x over previous
//
#include <hip/hip_runtime.h>
#include <hip/hip_bf16.h>
#include <math.h>

#define TT 365
#define BT 23360
#define NPOS 425

typedef __hip_bfloat16 bf16;
typedef __attribute__((ext_vector_type(8))) short s16x8;
typedef __attribute__((ext_vector_type(4))) float f32x4;

__device__ __forceinline__ float b2f(bf16 v) { return __bfloat162float(v); }
__device__ __forceinline__ bf16  f2b(float v) { return __float2bfloat16(v); }
__device__ __forceinline__ float u2f(unsigned u) { return __uint_as_float(u); }
__device__ __forceinline__ short f2bs(float v) { bf16 h = __float2bfloat16(v); return *reinterpret_cast<short*>(&h); }
__device__ __forceinline__ void unpack8(uint4 raw, float* v) {
    v[0] = u2f(raw.x << 16); v[1] = u2f(raw.x & 0xffff0000u);
    v[2] = u2f(raw.y << 16); v[3] = u2f(raw.y & 0xffff0000u);
    v[4] = u2f(raw.z << 16); v[5] = u2f(raw.z & 0xffff0000u);
    v[6] = u2f(raw.w << 16); v[7] = u2f(raw.w & 0xffff0000u);
}

// ---------------- prep: zero stats/pooled/esum, split-cast weights (PACKED), pos table ----------
// Packed layout per matrix: P(out,k) = ((out>>6)*(K/8) + (k>>3))*512 + (out&63)*8 + (k&7)
// == exactly the GEMM's LDS layout [colblock][kgroup][col][8] so staging is a contiguous copy.
// whi/wlo element offsets: w2@0(8192,K=64) w3@8192(32768,K=128) wi@40960(65536,K=256)
__global__ __launch_bounds__(256) void prep_kernel(
    float* __restrict__ stats, float* __restrict__ pooled, float* __restrict__ esum,
    const float* __restrict__ w2, const float* __restrict__ w3, const float* __restrict__ wi,
    bf16* __restrict__ whi, bf16* __restrict__ wlo, float* __restrict__ tab)
{
    int i = blockIdx.x * 256 + threadIdx.x;
    if (i < 2048)  { stats[i] = 0.f; return; }  i -= 2048;
    if (i < 16384) { pooled[i] = 0.f; return; } i -= 16384;
    if (i < 16384) { esum[i] = 0.f; return; }   i -= 16384;
    if (i < 106496) {
        float w; int out, k, Kq, base;
        if (i < 8192)       { int j = i;         Kq = 64;  out = j >> 6; k = j & 63;  base = 0;     w = w2[j]; }
        else if (i < 40960) { int j = i - 8192;  Kq = 128; out = j >> 7; k = j & 127; base = 8192;  w = w3[j]; }
        else                { int j = i - 40960; Kq = 256; out = j >> 8; k = j & 255; base = 40960; w = wi[j]; }
        int P = base + ((out >> 6) * (Kq >> 3) + (k >> 3)) * 512 + (out & 63) * 8 + (k & 7);
        bf16 h = f2b(w);
        whi[P] = h;
        wlo[P] = f2b(w - b2f(h));
        return;
    } i -= 106496;
    if (i < 108800) {
        int c = i & 255, p = i >> 8;
        float e = (float)(2 * (c >> 1)) * (1.f / 256.f);
        float ang = (float)p * exp2f(-e * 9.96578428466209f);   // 1000^-e
        tab[i] = (c & 1) ? cosf(ang) : sinf(ang);
    }
}

// ---------------- L1 GEMM (K=10, f32 A): Y[M,64](bf16) = x @ w1^T + b1; fused BN stats ----------
__global__ __launch_bounds__(256) void gemm_l1_kernel(
    const float* __restrict__ x,
    const float* __restrict__ W, const float* __restrict__ bias,
    bf16* __restrict__ Y, float* __restrict__ stats)
{
    const int t  = threadIdx.x;
    const int tx = t & 15, ty = t >> 4;
    const int row0 = blockIdx.x * 64;
    __shared__ float As[64][17];
    __shared__ float Ws[16][65];
    __shared__ float red_s[4][64];
    __shared__ float red_q[4][64];
    float acc[4][4];
#pragma unroll
    for (int rr = 0; rr < 4; ++rr)
#pragma unroll
        for (int cc = 0; cc < 4; ++cc) acc[rr][cc] = 0.f;
#pragma unroll
    for (int i = 0; i < 4; ++i) {
        int idx = t + i * 256, r = idx >> 4, c = idx & 15;
        As[r][c] = (c < 10) ? x[(size_t)(row0 + r) * 10 + c] : 0.f;
    }
#pragma unroll
    for (int i = 0; i < 4; ++i) {
        int idx = t + i * 256, c = idx >> 4, kk = idx & 15;
        Ws[kk][c] = (kk < 10) ? W[(size_t)c * 10 + kk] : 0.f;
    }
    __syncthreads();
#pragma unroll
    for (int kk = 0; kk < 10; ++kk) {
        float a[4];
#pragma unroll
        for (int rr = 0; rr < 4; ++rr) a[rr] = As[ty * 4 + rr][kk];
#pragma unroll
        for (int cc = 0; cc < 4; ++cc) {
            float w = Ws[kk][cc * 16 + tx];
#pragma unroll
            for (int rr = 0; rr < 4; ++rr) acc[rr][cc] = fmaf(a[rr], w, acc[rr][cc]);
        }
    }
    float s_cc[4], q_cc[4];
#pragma unroll
    for (int cc = 0; cc < 4; ++cc) { s_cc[cc] = 0.f; q_cc[cc] = 0.f; }
#pragma unroll
    for (int rr = 0; rr < 4; ++rr) {
        int row = row0 + ty * 4 + rr;
#pragma unroll
        for (int cc = 0; cc < 4; ++cc) {
            int col = cc * 16 + tx;
            float v = acc[rr][cc] + bias[col];
            Y[(size_t)row * 64 + col] = f2b(v);
            s_cc[cc] += v; q_cc[cc] += v * v;
        }
    }
    int w = t >> 6;
#pragma unroll
    for (int cc = 0; cc < 4; ++cc) {
        float s = s_cc[cc], q = q_cc[cc];
        s += __shfl_xor(s, 16); q += __shfl_xor(q, 16);
        s += __shfl_xor(s, 32); q += __shfl_xor(q, 32);
        if ((t & 63) < 16) { red_s[w][cc * 16 + tx] = s; red_q[w][cc * 16 + tx] = q; }
    }
    __syncthreads();
    if (t < 64) {
        float s = red_s[0][t] + red_s[1][t] + red_s[2][t] + red_s[3][t];
        float q = red_q[0][t] + red_q[1][t] + red_q[2][t] + red_q[3][t];
        atomicAdd(&stats[t], s);
        atomicAdd(&stats[256 + t], q);
    }
}

// ---------------- MFMA GEMM, LDS-staged W (packed, coalesced), A prefetched to registers -------
// MODE 1: A = relu(bn(y)). MODE 2: A = relu(bn(y)) + se[b,k].
// 1-D grid of 365*NCB blocks with XCD-aware bijective swizzle (m204): the NCB col-blocks
// sharing one A row-block run on the SAME XCD -> A hits that XCD's L2 instead of re-fetching.
template<int MODE, int K, int NCB>
__global__ __launch_bounds__(256) void mfma_gemm(
    const bf16* __restrict__ A,
    const bf16* __restrict__ Whi, const bf16* __restrict__ Wlo,
    const float* __restrict__ bias,
    bf16* __restrict__ Y, int ldY, float* __restrict__ stats,
    const float* __restrict__ bnstats, const float* __restrict__ bng,
    const float* __restrict__ bnb, const float* __restrict__ sebuf)
{
    constexpr int KC = (K > 128) ? 128 : K;      // staged chunk
    constexpr int VPC = (KC / 8) * 64;           // 16B vectors per (hi|lo) buffer per chunk
    __shared__ s16x8 Wl[2][KC / 8][64];          // [hi/lo][kgroup][col]
    __shared__ float red_s[4][64];
    __shared__ float red_q[4][64];
    __shared__ float scb[MODE ? K : 1];
    __shared__ float shb[MODE ? K : 1];
    const int t = threadIdx.x, wave = t >> 6, lane = t & 63;
    const int n16 = lane & 15, quad = lane >> 4;
    // XCD swizzle: physical bid -> logical tile L; consecutive L on one XCD
    constexpr int nwg = 365 * NCB;
    constexpr int sq = nwg >> 3, sr = nwg & 7;
    const int xcd = blockIdx.x & 7, sidx = blockIdx.x >> 3;
    const int L = (xcd < sr ? xcd * (sq + 1) : sr * (sq + 1) + (xcd - sr) * sq) + sidx;
    const int rowblk = L / NCB, colblk = L - rowblk * NCB;
    const int m0 = rowblk * 64 + wave * 16;
    const int col0 = colblk * 64;
    // packed weight base for this col-block (contiguous [kgroup][col][8])
    const s16x8* gH = (const s16x8*)Whi + (size_t)colblk * (K >> 3) * 64;
    const s16x8* gL = (const s16x8*)Wlo + (size_t)colblk * (K >> 3) * 64;
    s16x8* WlF = (s16x8*)Wl;
    // stage chunk 0 (fully coalesced contiguous copy) + BN coeffs
#pragma unroll
    for (int idx = t; idx < VPC; idx += 256) {
        WlF[idx]       = gH[idx];
        WlF[VPC + idx] = gL[idx];
    }
    if (MODE) {
        if (t < K) {
            float mu = bnstats[t] * (1.f / (float)BT);
            float var = bnstats[256 + t] * (1.f / (float)BT) - mu * mu;
            float sc = rsqrtf(var + 1e-5f) * bng[t];
            scb[t] = sc; shb[t] = bnb[t] - mu * sc;
        }
    }
    __syncthreads();
    // prefetch + transform all A fragments
    const int arow = m0 + n16;
    const float* sev = (MODE == 2) ? (sebuf + (arow / TT) * 256) : nullptr;
    const bf16* Ap = A + (size_t)arow * K + quad * 8;
    s16x8 af[K / 32];
#pragma unroll
    for (int i = 0; i < K / 32; ++i) {
        s16x8 raw = *(const s16x8*)(Ap + i * 32);
        if (MODE) {
            int kb = i * 32 + quad * 8;
#pragma unroll
            for (int j = 0; j < 8; ++j) {
                float y = u2f(((unsigned)(unsigned short)raw[j]) << 16);
                float v = fmaxf(fmaf(y, scb[kb + j], shb[kb + j]), 0.f);
                if (MODE == 2) v += sev[kb + j];
                raw[j] = f2bs(v);
            }
        }
        af[i] = raw;
    }
    f32x4 acc[4];
    f32x4 zero = {0.f, 0.f, 0.f, 0.f};
#pragma unroll
    for (int ct = 0; ct < 4; ++ct) acc[ct] = zero;
    // K loop over staged chunks
#pragma unroll
    for (int kc = 0; kc < K; kc += KC) {
        if (kc) {
            __syncthreads();   // all waves done with previous chunk
#pragma unroll
            for (int idx = t; idx < VPC; idx += 256) {
                WlF[idx]       = gH[(kc >> 3) * 64 + idx];
                WlF[VPC + idx] = gL[(kc >> 3) * 64 + idx];
            }
            __syncthreads();
        }
#pragma unroll
        for (int i = 0; i < KC / 32; ++i) {
            const int kgq = i * 4 + quad;
            const s16x8 a = af[(kc >> 5) + i];
#pragma unroll
            for (int ct = 0; ct < 4; ++ct) {
                s16x8 bl = Wl[1][kgq][ct * 16 + n16];
                s16x8 bh = Wl[0][kgq][ct * 16 + n16];
                acc[ct] = __builtin_amdgcn_mfma_f32_16x16x32_bf16(a, bl, acc[ct], 0, 0, 0);
                acc[ct] = __builtin_amdgcn_mfma_f32_16x16x32_bf16(a, bh, acc[ct], 0, 0, 0);
            }
        }
    }
    // epilogue (round-5 proven): bias, direct store, BN stats
#pragma unroll
    for (int ct = 0; ct < 4; ++ct) {
        int col = col0 + ct * 16 + n16;
        float bv = bias[col];
        float s = 0.f, q = 0.f;
#pragma unroll
        for (int r = 0; r < 4; ++r) {
            float v = acc[ct][r] + bv;
            int row = m0 + quad * 4 + r;
            Y[(size_t)row * ldY + col] = f2b(v);
            s += v; q += v * v;
        }
        s += __shfl_xor(s, 16); q += __shfl_xor(q, 16);
        s += __shfl_xor(s, 32); q += __shfl_xor(q, 32);
        if (quad == 0) { red_s[wave][ct * 16 + n16] = s; red_q[wave][ct * 16 + n16] = q; }
    }
    if (stats) {
        __syncthreads();
        if (t < 64) {
            float s = red_s[0][t] + red_s[1][t] + red_s[2][t] + red_s[3][t];
            float q = red_q[0][t] + red_q[1][t] + red_q[2][t] + red_q[3][t];
            atomicAdd(&stats[col0 + t], s);
            atomicAdd(&stats[256 + col0 + t], q);
        }
    }
}

// ---------------- pool partial: pooled[b,f] += sum_rows relu(bn3(Y3)) ----------------
__global__ __launch_bounds__(256) void pool_partial_kernel(
    const bf16* __restrict__ Y3, const float* __restrict__ stats,
    const float* __restrict__ g3, const float* __restrict__ e3,
    float* __restrict__ pooled)
{
    const int b = blockIdx.x, part = blockIdx.y, t = threadIdx.x;
    const int cg = t & 31, rs = t >> 5;
    __shared__ float scb[256], shb[256];
    __shared__ float pp[8][256];
    {
        float mu = stats[t] * (1.f / (float)BT);
        float var = stats[256 + t] * (1.f / (float)BT) - mu * mu;
        float sc = rsqrtf(var + 1e-5f) * g3[t];
        scb[t] = sc; shb[t] = e3[t] - mu * sc;
    }
    __syncthreads();
    float acc[8] = {0.f,0.f,0.f,0.f,0.f,0.f,0.f,0.f};
    const int r0 = part * 46;
#pragma unroll
    for (int i = 0; i < 6; ++i) {
        int l = rs + i * 8;
        int r = r0 + l;
        if (l < 46 && r < TT) {
            uint4 raw = *(const uint4*)(Y3 + ((size_t)b * TT + r) * 256 + cg * 8);
            float v[8];
            unpack8(raw, v);
#pragma unroll
            for (int j = 0; j < 8; ++j)
                acc[j] += fmaxf(fmaf(v[j], scb[cg * 8 + j], shb[cg * 8 + j]), 0.f);
        }
    }
#pragma unroll
    for (int j = 0; j < 8; ++j) pp[rs][cg * 8 + j] = acc[j];
    __syncthreads();
    float s = 0.f;
#pragma unroll
    for (int r = 0; r < 8; ++r) s += pp[r][t];
    atomicAdd(&pooled[b * 256 + t], s);
}

// ---------------- SE MLP ----------------
__global__ __launch_bounds__(256) void se_mlp_kernel(const float* __restrict__ pooled,
                                                     const float* __restrict__ ws1,
                                                     const float* __restrict__ ws2,
                                                     float* __restrict__ se) {
    int b = blockIdx.x, f = threadIdx.x;
    __shared__ float pl[256];
    __shared__ float hidden[16];
    float p = pooled[b * 256 + f] * (1.f / (float)TT);
    pl[f] = p;
    __syncthreads();
    if (f < 16) {
        float h = 0.f;
        for (int k2 = 0; k2 < 256; ++k2) h = fmaf(pl[k2], ws1[f * 256 + k2], h);
        hidden[f] = fmaxf(h, 0.f);
    }
    __syncthreads();
    float a = 0.f;
    for (int k2 = 0; k2 < 16; ++k2) a = fmaf(hidden[k2], ws2[f * 16 + k2], a);
    a = 1.f / (1.f + expf(-a));
    se[b * 256 + f] = a * p;
}

// ---------------- BN + ReLU + positional add + fused esum column sums ----------------
__global__ __launch_bounds__(256) void bnrelu8_kernel(
    const bf16* __restrict__ Y, const float* __restrict__ stats,
    const float* __restrict__ g, const float* __restrict__ beta,
    bf16* __restrict__ Out, const float* __restrict__ tab, const int* __restrict__ pos,
    float* __restrict__ esum) {
    __shared__ float pe[8][256];
    const int t = threadIdx.x;
    int i = (blockIdx.x * 256 + t) * 8;
    int col = i & 255, row = i >> 8;
    uint4 raw = *(const uint4*)(Y + i);
    float v[8];
    unpack8(raw, v);
    const float invM = 1.f / (float)BT;
    const float* tr = tab + pos[row] * 256 + col;
    bf16 tmp[8] __attribute__((aligned(16)));
    float* pr = &pe[t >> 5][col];
#pragma unroll
    for (int j = 0; j < 8; ++j) {
        float mu  = stats[col + j] * invM;
        float var = stats[256 + col + j] * invM - mu * mu;
        float o = (v[j] - mu) * rsqrtf(var + 1e-5f) * g[col + j] + beta[col + j];
        float ev = fmaxf(o, 0.f) + tr[j];
        tmp[j] = f2b(ev);
        pr[j] = ev;
    }
    *(uint4*)(Out + i) = *(const uint4*)tmp;
    __syncthreads();
    const int g0 = blockIdx.x * 8;          // global row of block-row 0
    const int b0 = g0 / TT, b1 = (g0 + 7) / TT;
    const int split = (b1 != b0) ? (b1 * TT - g0) : 8;
    float s0 = 0.f, s1 = 0.f;
#pragma unroll
    for (int rr = 0; rr < 8; ++rr) {
        float vv = pe[rr][t];
        if (rr < split) s0 += vv; else s1 += vv;
    }
    atomicAdd(&esum[b0 * 256 + t], s0);
    if (b1 != b0) atomicAdd(&esum[b1 * 256 + t], s1);
}

// ---------------- attention v3: one wave per (b,h); q-projection fused away ----------------
__global__ __launch_bounds__(64) void attn3_kernel(
    const bf16* __restrict__ e, const float* __restrict__ esum,
    const float* __restrict__ wk, const float* __restrict__ bk,
    const float* __restrict__ wq, const float* __restrict__ bq,
    float* __restrict__ yv)
{
    __shared__ float kqL[256];
    __shared__ float aw[368];
    const int b = blockIdx.x, h = blockIdx.y;
    const int lane = threadIdx.x;
    // ks[8] from esum (lane covers cols lane*4..+4)
    float4 es = *(const float4*)(esum + b * 256 + lane * 4);
    float ks[8];
#pragma unroll
    for (int d = 0; d < 8; ++d) {
        float4 wv = *(const float4*)(wk + (size_t)(h * 8 + d) * 256 + lane * 4);
        ks[d] = es.x * wv.x + es.y * wv.y + es.z * wv.z + es.w * wv.w;
    }
#pragma unroll
    for (int off = 1; off < 64; off <<= 1)
#pragma unroll
        for (int d = 0; d < 8; ++d) ks[d] += __shfl_xor(ks[d], off);
#pragma unroll
    for (int d = 0; d < 8; ++d) ks[d] += (float)TT * bk[h * 8 + d];
    // kq for my 4 cols; cb = bq_h . ks (same on all lanes)
    {
        float4 kq = {0.f, 0.f, 0.f, 0.f};
#pragma unroll
        for (int d = 0; d < 8; ++d) {
            float4 wv = *(const float4*)(wq + (size_t)(h * 8 + d) * 256 + lane * 4);
            kq.x = fmaf(ks[d], wv.x, kq.x);
            kq.y = fmaf(ks[d], wv.y, kq.y);
            kq.z = fmaf(ks[d], wv.z, kq.z);
            kq.w = fmaf(ks[d], wv.w, kq.w);
        }
        *(float4*)&kqL[lane * 4] = kq;
    }
    float cb = 0.f;
#pragma unroll
    for (int d = 0; d < 8; ++d) cb = fmaf(ks[d], bq[h * 8 + d], cb);
    __syncthreads();
    // scores: 8 groups of 8 lanes; group g handles rows r = it*8+g; lane covers 32 cols
    const int gp = lane >> 3, gl = lane & 7;
    float4 kr[8];
    {
        const float4* kq4 = (const float4*)(kqL + gl * 32);
#pragma unroll
        for (int u = 0; u < 8; ++u) kr[u] = kq4[u];
    }
    const float scale = 1.f / (sqrtf(8.f) * (float)TT);
    const bf16* ebs = e + (size_t)b * TT * 256 + gl * 32;
    for (int it = 0; it < 46; ++it) {
        int r = it * 8 + gp;
        if (r < TT) {
            const bf16* ep = ebs + (size_t)r * 256;
            float dot = 0.f;
#pragma unroll
            for (int u = 0; u < 4; ++u) {
                uint4 raw = *(const uint4*)(ep + u * 8);
                float v[8];
                unpack8(raw, v);
                float4 ka = kr[u * 2], kb2 = kr[u * 2 + 1];
                dot += v[0] * ka.x + v[1] * ka.y + v[2] * ka.z + v[3] * ka.w
                     + v[4] * kb2.x + v[5] * kb2.y + v[6] * kb2.z + v[7] * kb2.w;
            }
            dot += __shfl_xor(dot, 1);
            dot += __shfl_xor(dot, 2);
            dot += __shfl_xor(dot, 4);
            if (gl == 0) aw[r] = (dot + cb) * scale;
        }
    }
    __syncthreads();
    // softmax over rows (lane covers 6 rows)
    float sv[6];
    float m = -1e30f;
#pragma unroll
    for (int i = 0; i < 6; ++i) {
        int r = lane + i * 64;
        sv[i] = (r < TT) ? aw[r] : -1e30f;
        m = fmaxf(m, sv[i]);
    }
#pragma unroll
    for (int off = 1; off < 64; off <<= 1) m = fmaxf(m, __shfl_xor(m, off));
    float sum = 0.f;
#pragma unroll
    for (int i = 0; i < 6; ++i) {
        float ev = (sv[i] > -1e29f) ? expf(sv[i] - m) : 0.f;
        sv[i] = ev; sum += ev;
    }
#pragma unroll
    for (int off = 1; off < 64; off <<= 1) sum += __shfl_xor(sum, off);
    float inv = 1.f / sum;
#pragma unroll
    for (int i = 0; i < 6; ++i) {
        int r = lane + i * 64;
        if (r < TT) aw[r] = sv[i] * inv;
    }
    __syncthreads();
    // yv[b, h*16 + half*8 + j] = sum_r aw[r] * e[b,r,col]
    const int half = lane & 1, rs = lane >> 1;
    float acc[8] = {0.f,0.f,0.f,0.f,0.f,0.f,0.f,0.f};
    const bf16* ebase = e + (size_t)b * TT * 256 + h * 16 + half * 8;
#pragma unroll
    for (int i = 0; i < 12; ++i) {
        int r = rs + i * 32;
        if (r < TT) {
            uint4 raw = *(const uint4*)(ebase + (size_t)r * 256);
            float v[8];
            unpack8(raw, v);
            float a = aw[r];
#pragma unroll
            for (int j = 0; j < 8; ++j) acc[j] = fmaf(a, v[j], acc[j]);
        }
    }
#pragma unroll
    for (int off = 2; off < 64; off <<= 1)
#pragma unroll
        for (int j = 0; j < 8; ++j) acc[j] += __shfl_xor(acc[j], off);
    if (lane < 2) {
        float* op = yv + b * 256 + h * 16 + half * 8;
#pragma unroll
        for (int j = 0; j < 8; ++j) op[j] = acc[j];
    }
}

// ---------------- tail v4: column-parallel split of the PROVEN v2 tail ----------------

// layer m: 256 -> 128. grid 16; wave cw handles cols c0=bx*8+cw*2, c0+1.
__global__ __launch_bounds__(256) void tail_m_kernel(
    const float* __restrict__ yv, const float* __restrict__ wm,
    const float* __restrict__ gm, const float* __restrict__ em,
    float* __restrict__ z1)
{
    __shared__ float Xq[4160];           // [64k][65]
    const int t = threadIdx.x, r = t & 63, cw = t >> 6;
    const int c0 = blockIdx.x * 8 + cw * 2;
    const float4* wf4 = (const float4*)wm;   // [128][64 float4]
    float acc[2] = {0.f, 0.f};
    for (int p = 0; p < 4; ++p) {
        if (p) __syncthreads();
        for (int i = t; i < 4096; i += 256) {
            int kk = i & 63, rr = i >> 6;
            Xq[kk * 65 + rr] = yv[rr * 256 + p * 64 + kk];
        }
        __syncthreads();
#pragma unroll 4
        for (int k4 = 0; k4 < 16; ++k4) {
            float xv[4];
#pragma unroll
            for (int j = 0; j < 4; ++j) xv[j] = Xq[(k4 * 4 + j) * 65 + r];
#pragma unroll
            for (int c = 0; c < 2; ++c) {
                float4 w = wf4[(c0 + c) * 64 + p * 16 + k4];
                acc[c] = fmaf(xv[0], w.x, acc[c]);
                acc[c] = fmaf(xv[1], w.y, acc[c]);
                acc[c] = fmaf(xv[2], w.z, acc[c]);
                acc[c] = fmaf(xv[3], w.w, acc[c]);
            }
        }
    }
#pragma unroll
    for (int c = 0; c < 2; ++c) {
        float v = acc[c];
        float s = v, q = v * v;
#pragma unroll
        for (int off = 1; off < 64; off <<= 1) { s += __shfl_xor(s, off); q += __shfl_xor(q, off); }
        float mu = s * (1.f / 64.f), var = q * (1.f / 64.f) - mu * mu;
        float sc = rsqrtf(var + 1e-5f) * gm[c0 + c], sh = em[c0 + c] - mu * sc;
        z1[r * 128 + c0 + c] = fmaxf(fmaf(v, sc, sh), 0.f);
    }
}

// layer d1: 128 -> 64. grid 8; wave cw handles cols c0=bx*8+cw*2, c0+1.
__global__ __launch_bounds__(256) void tail_d1_kernel(
    const float* __restrict__ z1, const float* __restrict__ wd1,
    const float* __restrict__ gd1, const float* __restrict__ ed1,
    float* __restrict__ z2)
{
    __shared__ float Xq[4160];
    const int t = threadIdx.x, r = t & 63, cw = t >> 6;
    const int c0 = blockIdx.x * 8 + cw * 2;
    const float4* wf4 = (const float4*)wd1;  // [64][32 float4]
    float acc[2] = {0.f, 0.f};
    for (int p = 0; p < 2; ++p) {
        if (p) __syncthreads();
        for (int i = t; i < 4096; i += 256) {
            int kk = i & 63, rr = i >> 6;
            Xq[kk * 65 + rr] = z1[rr * 128 + p * 64 + kk];
        }
        __syncthreads();
#pragma unroll 4
        for (int k4 = 0; k4 < 16; ++k4) {
            float xv[4];
#pragma unroll
            for (int j = 0; j < 4; ++j) xv[j] = Xq[(k4 * 4 + j) * 65 + r];
#pragma unroll
            for (int c = 0; c < 2; ++c) {
                float4 w = wf4[(c0 + c) * 32 + p * 16 + k4];
                acc[c] = fmaf(xv[0], w.x, acc[c]);
                acc[c] = fmaf(xv[1], w.y, acc[c]);
                acc[c] = fmaf(xv[2], w.z, acc[c]);
                acc[c] = fmaf(xv[3], w.w, acc[c]);
            }
        }
    }
#pragma unroll
    for (int c = 0; c < 2; ++c) {
        float v = acc[c];
        float s = v, q = v * v;
#pragma unroll
        for (int off = 1; off < 64; off <<= 1) { s += __shfl_xor(s, off); q += __shfl_xor(q, off); }
        float mu = s * (1.f / 64.f), var = q * (1.f / 64.f) - mu * mu;
        float sc = rsqrtf(var + 1e-5f) * gd1[c0 + c], sh = ed1[c0 + c] - mu * sc;
        z2[r * 64 + c0 + c] = fmaxf(fmaf(v, sc, sh), 0.f);
    }
}

// layer d2 (64 -> 32) + classifier (32 -> 10). 1 block x 256thr; wave cw = 8 cols.
__global__ __launch_bounds__(256) void tail_d2c_kernel(
    const float* __restrict__ z2, const float* __restrict__ wd2,
    const float* __restrict__ gd2, const float* __restrict__ ed2,
    const float* __restrict__ wc, const float* __restrict__ bc,
    float* __restrict__ out)
{
    __shared__ float Xq[4160];           // [64k][65]
    __shared__ float Z3t[2048];          // [32][64]
    __shared__ float WcL[320];           // [10][32]
    const int t = threadIdx.x, r = t & 63, cw = t >> 6;
    const int c03 = cw * 8;
    for (int i = t; i < 4096; i += 256) {
        int kk = i & 63, rr = i >> 6;
        Xq[kk * 65 + rr] = z2[rr * 64 + kk];
    }
    if (t < 80) ((float4*)WcL)[t] = ((const float4*)wc)[t];
    __syncthreads();
    const float4* wf4 = (const float4*)wd2;  // [32][16 float4]
    float acc[8] = {0.f,0.f,0.f,0.f,0.f,0.f,0.f,0.f};
#pragma unroll 4
    for (int k4 = 0; k4 < 16; ++k4) {
        float xv[4];
#pragma unroll
        for (int j = 0; j < 4; ++j) xv[j] = Xq[(k4 * 4 + j) * 65 + r];
#pragma unroll
        for (int c = 0; c < 8; ++c) {
            float4 w = wf4[(c03 + c) * 16 + k4];
            acc[c] = fmaf(xv[0], w.x, acc[c]);
            acc[c] = fmaf(xv[1], w.y, acc[c]);
            acc[c] = fmaf(xv[2], w.z, acc[c]);
            acc[c] = fmaf(xv[3], w.w, acc[c]);
        }
    }
#pragma unroll
    for (int c = 0; c < 8; ++c) {
        float v = acc[c];
        float s = v, q = v * v;
#pragma unroll
        for (int off = 1; off < 64; off <<= 1) { s += __shfl_xor(s, off); q += __shfl_xor(q, off); }
        float mu = s * (1.f / 64.f), var = q * (1.f / 64.f) - mu * mu;
        float sc = rsqrtf(var + 1e-5f) * gd2[c03 + c], sh = ed2[c03 + c] - mu * sc;
        Z3t[(c03 + c) * 64 + r] = fmaxf(fmaf(v, sc, sh), 0.f);
    }
    __syncthreads();
#pragma unroll
    for (int i = 0; i < 3; ++i) {
        int idx = t + i * 256;
        if (idx < 640) {
            int rr = idx / 10, c = idx - rr * 10;
            float s = bc[c];
#pragma unroll
            for (int kk = 0; kk < 32; ++kk) s = fmaf(Z3t[kk * 64 + rr], WcL[c * 32 + kk], s);
            out[idx] = s;
        }
    }
}

// ---------------- launch ----------------

extern "C" void kernel_launch(void* const* d_in, const int* in_sizes, int n_in,
                              void* d_out, int out_size, void* d_ws, size_t ws_size,
                              hipStream_t stream) {
    (void)in_sizes; (void)n_in; (void)out_size; (void)ws_size;
    const float* x  = (const float*)d_in[0];
    const int* pos  = (const int*)d_in[1];
    const float *w1 = (const float*)d_in[2],  *b1 = (const float*)d_in[3],
                *g1 = (const float*)d_in[4],  *e1 = (const float*)d_in[5];
    const float *w2 = (const float*)d_in[6],  *b2 = (const float*)d_in[7],
                *g2 = (const float*)d_in[8],  *e2 = (const float*)d_in[9];
    const float *w3 = (const float*)d_in[10], *b3 = (const float*)d_in[11],
                *g3 = (const float*)d_in[12], *e3 = (const float*)d_in[13];
    const float *ws1 = (const float*)d_in[14], *ws2 = (const float*)d_in[15];
    const float *wi = (const float*)d_in[16], *bi = (const float*)d_in[17],
                *gi = (const float*)d_in[18], *ei = (const float*)d_in[19];
    const float *wk = (const float*)d_in[20], *bk = (const float*)d_in[21];   // k before q!
    const float *wq = (const float*)d_in[22], *bq = (const float*)d_in[23];
    const float *wm = (const float*)d_in[24], *bm = (const float*)d_in[25],
                *gm = (const float*)d_in[26], *em = (const float*)d_in[27];
    const float *wd1 = (const float*)d_in[28], *bd1 = (const float*)d_in[29],
                *gd1 = (const float*)d_in[30], *ed1 = (const float*)d_in[31];
    const float *wd2 = (const float*)d_in[32], *bd2 = (const float*)d_in[33],
                *gd2 = (const float*)d_in[34], *ed2 = (const float*)d_in[35];
    const float *wc = (const float*)d_in[36], *bc = (const float*)d_in[37];
    float* out = (float*)d_out;
    (void)bm; (void)bd1; (void)bd2;   // linear biases cancel under train-mode BN

    char* w8 = (char*)d_ws;
    bf16*  actA   = (bf16*)(w8);                    // 11,960,320
    bf16*  actB   = (bf16*)(w8 + 11960320);         // 11,960,320
    bf16*  whi    = (bf16*)(w8 + 23920640);         //    278,528
    bf16*  wlo    = (bf16*)(w8 + 24199168);         //    278,528
    float* tab    = (float*)(w8 + 24477696);        //    435,200
    float* stats  = (float*)(w8 + 24912896);        //      8,192
    float* pooled = (float*)(w8 + 24921088);        //     65,536
    float* sebuf  = (float*)(w8 + 24986624);        //     65,536
    float* esum   = (float*)(w8 + 25052160);        //     65,536
    float* yvb    = (float*)(w8 + 25117696);        //     65,536
    // tail intermediates reuse regions that are dead after attn (rewritten by prep each launch)
    float* z1     = esum;        // 32,768 of 65,536 (esum last read by attn3)
    float* z2     = sebuf;       // 16,384 of 65,536 (sebuf last read by inconv gemm)

    prep_kernel<<<977, 256, 0, stream>>>(stats, pooled, esum, w2, w3, wi, whi, wlo, tab);
    // L1: 10 -> 64 -> Y1 = actB + stats1
    gemm_l1_kernel<<<365, 256, 0, stream>>>(x, w1, b1, actB, stats);
    // L2: 64 -> 128, fused BN1 -> Y2 = actA + stats2
    mfma_gemm<1, 64, 2><<<730, 256, 0, stream>>>(actB, whi, wlo, b2,
                                                 actA, 128, stats + 512, stats, g1, e1, nullptr);
    // L3: 128 -> 256, fused BN2 -> Y3 = actB + stats3
    mfma_gemm<1, 128, 4><<<1460, 256, 0, stream>>>(actA, whi + 8192, wlo + 8192, b3,
                                                   actB, 256, stats + 1024, stats + 512, g2, e2, nullptr);
    // pool (fused BN3+relu) -> pooled; SE MLP -> sebuf
    pool_partial_kernel<<<dim3(64, 8), 256, 0, stream>>>(actB, stats + 1024, g3, e3, pooled);
    se_mlp_kernel<<<64, 256, 0, stream>>>(pooled, ws1, ws2, sebuf);
    // inconv: A = Y3 with fused BN3+relu+SE-residual -> Yi = actA + statsi
    mfma_gemm<2, 256, 4><<<1460, 256, 0, stream>>>(actB, whi + 40960, wlo + 40960, bi,
                                                   actA, 256, stats + 1536, stats + 1024, g3, e3, sebuf);
    // bn_i + relu + PE -> e = actB; esum fused
    bnrelu8_kernel<<<BT * 256 / 2048, 256, 0, stream>>>(actA, stats + 1536, gi, ei, actB, tab, pos, esum);
    // attention v3: q GEMM fused away via kq = wq^T.ks
    attn3_kernel<<<dim3(64, 16), 64, 0, stream>>>(actB, esum, wk, bk, wq, bq, yvb);
    // tail v4: column-parallel, v2-proven building blocks
    tail_m_kernel<<<16, 256, 0, stream>>>(yvb, wm, gm, em, z1);
    tail_d1_kernel<<<8, 256, 0, stream>>>(z1, wd1, gd1, ed1, z2);
    tail_d2c_kernel<<<1, 256, 0, stream>>>(z2, wd2, gd2, ed2, wc, bc, out);
}

// Round 8
// 291.183 us; speedup vs baseline: 1.1065x; 1.0153x over previous
//
#include <hip/hip_runtime.h>
#include <hip/hip_bf16.h>
#include <math.h>

#define TT 365
#define BT 23360
#define NPOS 425

typedef __hip_bfloat16 bf16;
typedef __attribute__((ext_vector_type(8))) short s16x8;
typedef __attribute__((ext_vector_type(4))) float f32x4;

__device__ __forceinline__ float b2f(bf16 v) { return __bfloat162float(v); }
__device__ __forceinline__ bf16  f2b(float v) { return __float2bfloat16(v); }
__device__ __forceinline__ float u2f(unsigned u) { return __uint_as_float(u); }
__device__ __forceinline__ short f2bs(float v) { bf16 h = __float2bfloat16(v); return *reinterpret_cast<short*>(&h); }
__device__ __forceinline__ void unpack8(uint4 raw, float* v) {
    v[0] = u2f(raw.x << 16); v[1] = u2f(raw.x & 0xffff0000u);
    v[2] = u2f(raw.y << 16); v[3] = u2f(raw.y & 0xffff0000u);
    v[4] = u2f(raw.z << 16); v[5] = u2f(raw.z & 0xffff0000u);
    v[6] = u2f(raw.w << 16); v[7] = u2f(raw.w & 0xffff0000u);
}

// ---------------- prep: zero stats/pooled/esum, split-cast weights (PACKED), pos table ----------
// Packed layout per matrix: P(out,k) = ((out>>6)*(K/8) + (k>>3))*512 + (out&63)*8 + (k&7)
// == exactly the GEMM's LDS layout [colblock][kgroup][col][8] so staging is a contiguous copy.
// whi/wlo element offsets: w2@0(8192,K=64) w3@8192(32768,K=128) wi@40960(65536,K=256)
__global__ __launch_bounds__(256) void prep_kernel(
    float* __restrict__ stats, float* __restrict__ pooled, float* __restrict__ esum,
    const float* __restrict__ w2, const float* __restrict__ w3, const float* __restrict__ wi,
    bf16* __restrict__ whi, bf16* __restrict__ wlo, float* __restrict__ tab)
{
    int i = blockIdx.x * 256 + threadIdx.x;
    if (i < 2048)  { stats[i] = 0.f; return; }  i -= 2048;
    if (i < 16384) { pooled[i] = 0.f; return; } i -= 16384;
    if (i < 16384) { esum[i] = 0.f; return; }   i -= 16384;
    if (i < 106496) {
        float w; int out, k, Kq, base;
        if (i < 8192)       { int j = i;         Kq = 64;  out = j >> 6; k = j & 63;  base = 0;     w = w2[j]; }
        else if (i < 40960) { int j = i - 8192;  Kq = 128; out = j >> 7; k = j & 127; base = 8192;  w = w3[j]; }
        else                { int j = i - 40960; Kq = 256; out = j >> 8; k = j & 255; base = 40960; w = wi[j]; }
        int P = base + ((out >> 6) * (Kq >> 3) + (k >> 3)) * 512 + (out & 63) * 8 + (k & 7);
        bf16 h = f2b(w);
        whi[P] = h;
        wlo[P] = f2b(w - b2f(h));
        return;
    } i -= 106496;
    if (i < 108800) {
        int c = i & 255, p = i >> 8;
        float e = (float)(2 * (c >> 1)) * (1.f / 256.f);
        float ang = (float)p * exp2f(-e * 9.96578428466209f);   // 1000^-e
        tab[i] = (c & 1) ? cosf(ang) : sinf(ang);
    }
}

// ---------------- L1 GEMM (K=10, f32 A): Y[M,64](bf16) = x @ w1^T + b1; fused BN stats ----------
__global__ __launch_bounds__(256) void gemm_l1_kernel(
    const float* __restrict__ x,
    const float* __restrict__ W, const float* __restrict__ bias,
    bf16* __restrict__ Y, float* __restrict__ stats)
{
    const int t  = threadIdx.x;
    const int tx = t & 15, ty = t >> 4;
    const int row0 = blockIdx.x * 64;
    __shared__ float As[64][17];
    __shared__ float Ws[16][65];
    __shared__ float red_s[4][64];
    __shared__ float red_q[4][64];
    float acc[4][4];
#pragma unroll
    for (int rr = 0; rr < 4; ++rr)
#pragma unroll
        for (int cc = 0; cc < 4; ++cc) acc[rr][cc] = 0.f;
#pragma unroll
    for (int i = 0; i < 4; ++i) {
        int idx = t + i * 256, r = idx >> 4, c = idx & 15;
        As[r][c] = (c < 10) ? x[(size_t)(row0 + r) * 10 + c] : 0.f;
    }
#pragma unroll
    for (int i = 0; i < 4; ++i) {
        int idx = t + i * 256, c = idx >> 4, kk = idx & 15;
        Ws[kk][c] = (kk < 10) ? W[(size_t)c * 10 + kk] : 0.f;
    }
    __syncthreads();
#pragma unroll
    for (int kk = 0; kk < 10; ++kk) {
        float a[4];
#pragma unroll
        for (int rr = 0; rr < 4; ++rr) a[rr] = As[ty * 4 + rr][kk];
#pragma unroll
        for (int cc = 0; cc < 4; ++cc) {
            float w = Ws[kk][cc * 16 + tx];
#pragma unroll
            for (int rr = 0; rr < 4; ++rr) acc[rr][cc] = fmaf(a[rr], w, acc[rr][cc]);
        }
    }
    float s_cc[4], q_cc[4];
#pragma unroll
    for (int cc = 0; cc < 4; ++cc) { s_cc[cc] = 0.f; q_cc[cc] = 0.f; }
#pragma unroll
    for (int rr = 0; rr < 4; ++rr) {
        int row = row0 + ty * 4 + rr;
#pragma unroll
        for (int cc = 0; cc < 4; ++cc) {
            int col = cc * 16 + tx;
            float v = acc[rr][cc] + bias[col];
            Y[(size_t)row * 64 + col] = f2b(v);
            s_cc[cc] += v; q_cc[cc] += v * v;
        }
    }
    int w = t >> 6;
#pragma unroll
    for (int cc = 0; cc < 4; ++cc) {
        float s = s_cc[cc], q = q_cc[cc];
        s += __shfl_xor(s, 16); q += __shfl_xor(q, 16);
        s += __shfl_xor(s, 32); q += __shfl_xor(q, 32);
        if ((t & 63) < 16) { red_s[w][cc * 16 + tx] = s; red_q[w][cc * 16 + tx] = q; }
    }
    __syncthreads();
    if (t < 64) {
        float s = red_s[0][t] + red_s[1][t] + red_s[2][t] + red_s[3][t];
        float q = red_q[0][t] + red_q[1][t] + red_q[2][t] + red_q[3][t];
        atomicAdd(&stats[t], s);
        atomicAdd(&stats[256 + t], q);
    }
}

// ---------------- MFMA GEMM, LDS-staged W (packed, coalesced), A prefetched to registers -------
// MODE 1: A = relu(bn(y)). MODE 2: A = relu(bn(y)) + se[b,k].
// KC=64: LDS ~20.5KB -> 7 blocks/CU (was 4 at KC=128); all 1460 blocks co-resident.
// A-prefetch issued BEFORE W staging so cold-HBM A latency overlaps staging + barrier.
// XCD-aware bijective swizzle (m204): NCB col-blocks sharing an A row-block run on one XCD.
template<int MODE, int K, int NCB>
__global__ __launch_bounds__(256) void mfma_gemm(
    const bf16* __restrict__ A,
    const bf16* __restrict__ Whi, const bf16* __restrict__ Wlo,
    const float* __restrict__ bias,
    bf16* __restrict__ Y, int ldY, float* __restrict__ stats,
    const float* __restrict__ bnstats, const float* __restrict__ bng,
    const float* __restrict__ bnb, const float* __restrict__ sebuf)
{
    constexpr int KC = 64;                       // staged chunk
    constexpr int VPC = (KC / 8) * 64;           // 16B vectors per (hi|lo) buffer per chunk
    __shared__ s16x8 Wl[2][KC / 8][64];          // [hi/lo][kgroup][col]
    __shared__ float red_s[4][64];
    __shared__ float red_q[4][64];
    __shared__ float scb[MODE ? K : 1];
    __shared__ float shb[MODE ? K : 1];
    const int t = threadIdx.x, wave = t >> 6, lane = t & 63;
    const int n16 = lane & 15, quad = lane >> 4;
    // XCD swizzle: physical bid -> logical tile L; consecutive L on one XCD
    constexpr int nwg = 365 * NCB;
    constexpr int sq = nwg >> 3, sr = nwg & 7;
    const int xcd = blockIdx.x & 7, sidx = blockIdx.x >> 3;
    const int L = (xcd < sr ? xcd * (sq + 1) : sr * (sq + 1) + (xcd - sr) * sq) + sidx;
    const int rowblk = L / NCB, colblk = L - rowblk * NCB;
    const int m0 = rowblk * 64 + wave * 16;
    const int col0 = colblk * 64;
    // ---- issue A prefetch FIRST (longest-latency cold loads) ----
    const int arow = m0 + n16;
    const bf16* Ap = A + (size_t)arow * K + quad * 8;
    s16x8 af[K / 32];
#pragma unroll
    for (int i = 0; i < K / 32; ++i) af[i] = *(const s16x8*)(Ap + i * 32);
    // packed weight base for this col-block (contiguous [kgroup][col][8])
    const s16x8* gH = (const s16x8*)Whi + (size_t)colblk * (K >> 3) * 64;
    const s16x8* gL = (const s16x8*)Wlo + (size_t)colblk * (K >> 3) * 64;
    s16x8* WlF = (s16x8*)Wl;
    // stage chunk 0 (fully coalesced contiguous copy) + BN coeffs
#pragma unroll
    for (int idx = t; idx < VPC; idx += 256) {
        WlF[idx]       = gH[idx];
        WlF[VPC + idx] = gL[idx];
    }
    if (MODE) {
        if (t < K) {
            float mu = bnstats[t] * (1.f / (float)BT);
            float var = bnstats[256 + t] * (1.f / (float)BT) - mu * mu;
            float sc = rsqrtf(var + 1e-5f) * bng[t];
            scb[t] = sc; shb[t] = bnb[t] - mu * sc;
        }
    }
    __syncthreads();
    // transform A fragments in place (needs scb/shb)
    if (MODE) {
        const float* sev = (MODE == 2) ? (sebuf + (arow / TT) * 256) : nullptr;
#pragma unroll
        for (int i = 0; i < K / 32; ++i) {
            s16x8 raw = af[i];
            int kb = i * 32 + quad * 8;
#pragma unroll
            for (int j = 0; j < 8; ++j) {
                float y = u2f(((unsigned)(unsigned short)raw[j]) << 16);
                float v = fmaxf(fmaf(y, scb[kb + j], shb[kb + j]), 0.f);
                if (MODE == 2) v += sev[kb + j];
                raw[j] = f2bs(v);
            }
            af[i] = raw;
        }
    }
    f32x4 acc[4];
    f32x4 zero = {0.f, 0.f, 0.f, 0.f};
#pragma unroll
    for (int ct = 0; ct < 4; ++ct) acc[ct] = zero;
    // K loop over staged chunks
#pragma unroll
    for (int kc = 0; kc < K; kc += KC) {
        if (kc) {
            __syncthreads();   // all waves done with previous chunk
#pragma unroll
            for (int idx = t; idx < VPC; idx += 256) {
                WlF[idx]       = gH[(kc >> 3) * 64 + idx];
                WlF[VPC + idx] = gL[(kc >> 3) * 64 + idx];
            }
            __syncthreads();
        }
#pragma unroll
        for (int i = 0; i < KC / 32; ++i) {
            const int kgq = i * 4 + quad;
            const s16x8 a = af[(kc >> 5) + i];
#pragma unroll
            for (int ct = 0; ct < 4; ++ct) {
                s16x8 bl = Wl[1][kgq][ct * 16 + n16];
                s16x8 bh = Wl[0][kgq][ct * 16 + n16];
                acc[ct] = __builtin_amdgcn_mfma_f32_16x16x32_bf16(a, bl, acc[ct], 0, 0, 0);
                acc[ct] = __builtin_amdgcn_mfma_f32_16x16x32_bf16(a, bh, acc[ct], 0, 0, 0);
            }
        }
    }
    // epilogue (round-5 proven): bias, direct store, BN stats
#pragma unroll
    for (int ct = 0; ct < 4; ++ct) {
        int col = col0 + ct * 16 + n16;
        float bv = bias[col];
        float s = 0.f, q = 0.f;
#pragma unroll
        for (int r = 0; r < 4; ++r) {
            float v = acc[ct][r] + bv;
            int row = m0 + quad * 4 + r;
            Y[(size_t)row * ldY + col] = f2b(v);
            s += v; q += v * v;
        }
        s += __shfl_xor(s, 16); q += __shfl_xor(q, 16);
        s += __shfl_xor(s, 32); q += __shfl_xor(q, 32);
        if (quad == 0) { red_s[wave][ct * 16 + n16] = s; red_q[wave][ct * 16 + n16] = q; }
    }
    if (stats) {
        __syncthreads();
        if (t < 64) {
            float s = red_s[0][t] + red_s[1][t] + red_s[2][t] + red_s[3][t];
            float q = red_q[0][t] + red_q[1][t] + red_q[2][t] + red_q[3][t];
            atomicAdd(&stats[col0 + t], s);
            atomicAdd(&stats[256 + col0 + t], q);
        }
    }
}

// ---------------- pool partial: pooled[b,f] += sum_rows relu(bn3(Y3)) ----------------
__global__ __launch_bounds__(256) void pool_partial_kernel(
    const bf16* __restrict__ Y3, const float* __restrict__ stats,
    const float* __restrict__ g3, const float* __restrict__ e3,
    float* __restrict__ pooled)
{
    const int b = blockIdx.x, part = blockIdx.y, t = threadIdx.x;
    const int cg = t & 31, rs = t >> 5;
    __shared__ float scb[256], shb[256];
    __shared__ float pp[8][256];
    {
        float mu = stats[t] * (1.f / (float)BT);
        float var = stats[256 + t] * (1.f / (float)BT) - mu * mu;
        float sc = rsqrtf(var + 1e-5f) * g3[t];
        scb[t] = sc; shb[t] = e3[t] - mu * sc;
    }
    __syncthreads();
    float acc[8] = {0.f,0.f,0.f,0.f,0.f,0.f,0.f,0.f};
    const int r0 = part * 46;
#pragma unroll
    for (int i = 0; i < 6; ++i) {
        int l = rs + i * 8;
        int r = r0 + l;
        if (l < 46 && r < TT) {
            uint4 raw = *(const uint4*)(Y3 + ((size_t)b * TT + r) * 256 + cg * 8);
            float v[8];
            unpack8(raw, v);
#pragma unroll
            for (int j = 0; j < 8; ++j)
                acc[j] += fmaxf(fmaf(v[j], scb[cg * 8 + j], shb[cg * 8 + j]), 0.f);
        }
    }
#pragma unroll
    for (int j = 0; j < 8; ++j) pp[rs][cg * 8 + j] = acc[j];
    __syncthreads();
    float s = 0.f;
#pragma unroll
    for (int r = 0; r < 8; ++r) s += pp[r][t];
    atomicAdd(&pooled[b * 256 + t], s);
}

// ---------------- SE MLP ----------------
__global__ __launch_bounds__(256) void se_mlp_kernel(const float* __restrict__ pooled,
                                                     const float* __restrict__ ws1,
                                                     const float* __restrict__ ws2,
                                                     float* __restrict__ se) {
    int b = blockIdx.x, f = threadIdx.x;
    __shared__ float pl[256];
    __shared__ float hidden[16];
    float p = pooled[b * 256 + f] * (1.f / (float)TT);
    pl[f] = p;
    __syncthreads();
    if (f < 16) {
        float h = 0.f;
        for (int k2 = 0; k2 < 256; ++k2) h = fmaf(pl[k2], ws1[f * 256 + k2], h);
        hidden[f] = fmaxf(h, 0.f);
    }
    __syncthreads();
    float a = 0.f;
    for (int k2 = 0; k2 < 16; ++k2) a = fmaf(hidden[k2], ws2[f * 16 + k2], a);
    a = 1.f / (1.f + expf(-a));
    se[b * 256 + f] = a * p;
}

// ---------------- BN + ReLU + positional add + fused esum column sums ----------------
__global__ __launch_bounds__(256) void bnrelu8_kernel(
    const bf16* __restrict__ Y, const float* __restrict__ stats,
    const float* __restrict__ g, const float* __restrict__ beta,
    bf16* __restrict__ Out, const float* __restrict__ tab, const int* __restrict__ pos,
    float* __restrict__ esum) {
    __shared__ float pe[8][256];
    const int t = threadIdx.x;
    int i = (blockIdx.x * 256 + t) * 8;
    int col = i & 255, row = i >> 8;
    uint4 raw = *(const uint4*)(Y + i);
    float v[8];
    unpack8(raw, v);
    const float invM = 1.f / (float)BT;
    const float* tr = tab + pos[row] * 256 + col;
    bf16 tmp[8] __attribute__((aligned(16)));
    float* pr = &pe[t >> 5][col];
#pragma unroll
    for (int j = 0; j < 8; ++j) {
        float mu  = stats[col + j] * invM;
        float var = stats[256 + col + j] * invM - mu * mu;
        float o = (v[j] - mu) * rsqrtf(var + 1e-5f) * g[col + j] + beta[col + j];
        float ev = fmaxf(o, 0.f) + tr[j];
        tmp[j] = f2b(ev);
        pr[j] = ev;
    }
    *(uint4*)(Out + i) = *(const uint4*)tmp;
    __syncthreads();
    const int g0 = blockIdx.x * 8;          // global row of block-row 0
    const int b0 = g0 / TT, b1 = (g0 + 7) / TT;
    const int split = (b1 != b0) ? (b1 * TT - g0) : 8;
    float s0 = 0.f, s1 = 0.f;
#pragma unroll
    for (int rr = 0; rr < 8; ++rr) {
        float vv = pe[rr][t];
        if (rr < split) s0 += vv; else s1 += vv;
    }
    atomicAdd(&esum[b0 * 256 + t], s0);
    if (b1 != b0) atomicAdd(&esum[b1 * 256 + t], s1);
}

// ---------------- attention v3: one wave per (b,h); q-projection fused away ----------------
__global__ __launch_bounds__(64) void attn3_kernel(
    const bf16* __restrict__ e, const float* __restrict__ esum,
    const float* __restrict__ wk, const float* __restrict__ bk,
    const float* __restrict__ wq, const float* __restrict__ bq,
    float* __restrict__ yv)
{
    __shared__ float kqL[256];
    __shared__ float aw[368];
    const int b = blockIdx.x, h = blockIdx.y;
    const int lane = threadIdx.x;
    // ks[8] from esum (lane covers cols lane*4..+4)
    float4 es = *(const float4*)(esum + b * 256 + lane * 4);
    float ks[8];
#pragma unroll
    for (int d = 0; d < 8; ++d) {
        float4 wv = *(const float4*)(wk + (size_t)(h * 8 + d) * 256 + lane * 4);
        ks[d] = es.x * wv.x + es.y * wv.y + es.z * wv.z + es.w * wv.w;
    }
#pragma unroll
    for (int off = 1; off < 64; off <<= 1)
#pragma unroll
        for (int d = 0; d < 8; ++d) ks[d] += __shfl_xor(ks[d], off);
#pragma unroll
    for (int d = 0; d < 8; ++d) ks[d] += (float)TT * bk[h * 8 + d];
    // kq for my 4 cols; cb = bq_h . ks (same on all lanes)
    {
        float4 kq = {0.f, 0.f, 0.f, 0.f};
#pragma unroll
        for (int d = 0; d < 8; ++d) {
            float4 wv = *(const float4*)(wq + (size_t)(h * 8 + d) * 256 + lane * 4);
            kq.x = fmaf(ks[d], wv.x, kq.x);
            kq.y = fmaf(ks[d], wv.y, kq.y);
            kq.z = fmaf(ks[d], wv.z, kq.z);
            kq.w = fmaf(ks[d], wv.w, kq.w);
        }
        *(float4*)&kqL[lane * 4] = kq;
    }
    float cb = 0.f;
#pragma unroll
    for (int d = 0; d < 8; ++d) cb = fmaf(ks[d], bq[h * 8 + d], cb);
    __syncthreads();
    // scores: 8 groups of 8 lanes; group g handles rows r = it*8+g; lane covers 32 cols
    const int gp = lane >> 3, gl = lane & 7;
    float4 kr[8];
    {
        const float4* kq4 = (const float4*)(kqL + gl * 32);
#pragma unroll
        for (int u = 0; u < 8; ++u) kr[u] = kq4[u];
    }
    const float scale = 1.f / (sqrtf(8.f) * (float)TT);
    const bf16* ebs = e + (size_t)b * TT * 256 + gl * 32;
    for (int it = 0; it < 46; ++it) {
        int r = it * 8 + gp;
        if (r < TT) {
            const bf16* ep = ebs + (size_t)r * 256;
            float dot = 0.f;
#pragma unroll
            for (int u = 0; u < 4; ++u) {
                uint4 raw = *(const uint4*)(ep + u * 8);
                float v[8];
                unpack8(raw, v);
                float4 ka = kr[u * 2], kb2 = kr[u * 2 + 1];
                dot += v[0] * ka.x + v[1] * ka.y + v[2] * ka.z + v[3] * ka.w
                     + v[4] * kb2.x + v[5] * kb2.y + v[6] * kb2.z + v[7] * kb2.w;
            }
            dot += __shfl_xor(dot, 1);
            dot += __shfl_xor(dot, 2);
            dot += __shfl_xor(dot, 4);
            if (gl == 0) aw[r] = (dot + cb) * scale;
        }
    }
    __syncthreads();
    // softmax over rows (lane covers 6 rows)
    float sv[6];
    float m = -1e30f;
#pragma unroll
    for (int i = 0; i < 6; ++i) {
        int r = lane + i * 64;
        sv[i] = (r < TT) ? aw[r] : -1e30f;
        m = fmaxf(m, sv[i]);
    }
#pragma unroll
    for (int off = 1; off < 64; off <<= 1) m = fmaxf(m, __shfl_xor(m, off));
    float sum = 0.f;
#pragma unroll
    for (int i = 0; i < 6; ++i) {
        float ev = (sv[i] > -1e29f) ? expf(sv[i] - m) : 0.f;
        sv[i] = ev; sum += ev;
    }
#pragma unroll
    for (int off = 1; off < 64; off <<= 1) sum += __shfl_xor(sum, off);
    float inv = 1.f / sum;
#pragma unroll
    for (int i = 0; i < 6; ++i) {
        int r = lane + i * 64;
        if (r < TT) aw[r] = sv[i] * inv;
    }
    __syncthreads();
    // yv[b, h*16 + half*8 + j] = sum_r aw[r] * e[b,r,col]
    const int half = lane & 1, rs = lane >> 1;
    float acc[8] = {0.f,0.f,0.f,0.f,0.f,0.f,0.f,0.f};
    const bf16* ebase = e + (size_t)b * TT * 256 + h * 16 + half * 8;
#pragma unroll
    for (int i = 0; i < 12; ++i) {
        int r = rs + i * 32;
        if (r < TT) {
            uint4 raw = *(const uint4*)(ebase + (size_t)r * 256);
            float v[8];
            unpack8(raw, v);
            float a = aw[r];
#pragma unroll
            for (int j = 0; j < 8; ++j) acc[j] = fmaf(a, v[j], acc[j]);
        }
    }
#pragma unroll
    for (int off = 2; off < 64; off <<= 1)
#pragma unroll
        for (int j = 0; j < 8; ++j) acc[j] += __shfl_xor(acc[j], off);
    if (lane < 2) {
        float* op = yv + b * 256 + h * 16 + half * 8;
#pragma unroll
        for (int j = 0; j < 8; ++j) op[j] = acc[j];
    }
}

// ---------------- tail v4: column-parallel split of the PROVEN v2 tail ----------------

// layer m: 256 -> 128. grid 16; wave cw handles cols c0=bx*8+cw*2, c0+1.
__global__ __launch_bounds__(256) void tail_m_kernel(
    const float* __restrict__ yv, const float* __restrict__ wm,
    const float* __restrict__ gm, const float* __restrict__ em,
    float* __restrict__ z1)
{
    __shared__ float Xq[4160];           // [64k][65]
    const int t = threadIdx.x, r = t & 63, cw = t >> 6;
    const int c0 = blockIdx.x * 8 + cw * 2;
    const float4* wf4 = (const float4*)wm;   // [128][64 float4]
    float acc[2] = {0.f, 0.f};
    for (int p = 0; p < 4; ++p) {
        if (p) __syncthreads();
        for (int i = t; i < 4096; i += 256) {
            int kk = i & 63, rr = i >> 6;
            Xq[kk * 65 + rr] = yv[rr * 256 + p * 64 + kk];
        }
        __syncthreads();
#pragma unroll 4
        for (int k4 = 0; k4 < 16; ++k4) {
            float xv[4];
#pragma unroll
            for (int j = 0; j < 4; ++j) xv[j] = Xq[(k4 * 4 + j) * 65 + r];
#pragma unroll
            for (int c = 0; c < 2; ++c) {
                float4 w = wf4[(c0 + c) * 64 + p * 16 + k4];
                acc[c] = fmaf(xv[0], w.x, acc[c]);
                acc[c] = fmaf(xv[1], w.y, acc[c]);
                acc[c] = fmaf(xv[2], w.z, acc[c]);
                acc[c] = fmaf(xv[3], w.w, acc[c]);
            }
        }
    }
#pragma unroll
    for (int c = 0; c < 2; ++c) {
        float v = acc[c];
        float s = v, q = v * v;
#pragma unroll
        for (int off = 1; off < 64; off <<= 1) { s += __shfl_xor(s, off); q += __shfl_xor(q, off); }
        float mu = s * (1.f / 64.f), var = q * (1.f / 64.f) - mu * mu;
        float sc = rsqrtf(var + 1e-5f) * gm[c0 + c], sh = em[c0 + c] - mu * sc;
        z1[r * 128 + c0 + c] = fmaxf(fmaf(v, sc, sh), 0.f);
    }
}

// layer d1: 128 -> 64. grid 8; wave cw handles cols c0=bx*8+cw*2, c0+1.
__global__ __launch_bounds__(256) void tail_d1_kernel(
    const float* __restrict__ z1, const float* __restrict__ wd1,
    const float* __restrict__ gd1, const float* __restrict__ ed1,
    float* __restrict__ z2)
{
    __shared__ float Xq[4160];
    const int t = threadIdx.x, r = t & 63, cw = t >> 6;
    const int c0 = blockIdx.x * 8 + cw * 2;
    const float4* wf4 = (const float4*)wd1;  // [64][32 float4]
    float acc[2] = {0.f, 0.f};
    for (int p = 0; p < 2; ++p) {
        if (p) __syncthreads();
        for (int i = t; i < 4096; i += 256) {
            int kk = i & 63, rr = i >> 6;
            Xq[kk * 65 + rr] = z1[rr * 128 + p * 64 + kk];
        }
        __syncthreads();
#pragma unroll 4
        for (int k4 = 0; k4 < 16; ++k4) {
            float xv[4];
#pragma unroll
            for (int j = 0; j < 4; ++j) xv[j] = Xq[(k4 * 4 + j) * 65 + r];
#pragma unroll
            for (int c = 0; c < 2; ++c) {
                float4 w = wf4[(c0 + c) * 32 + p * 16 + k4];
                acc[c] = fmaf(xv[0], w.x, acc[c]);
                acc[c] = fmaf(xv[1], w.y, acc[c]);
                acc[c] = fmaf(xv[2], w.z, acc[c]);
                acc[c] = fmaf(xv[3], w.w, acc[c]);
            }
        }
    }
#pragma unroll
    for (int c = 0; c < 2; ++c) {
        float v = acc[c];
        float s = v, q = v * v;
#pragma unroll
        for (int off = 1; off < 64; off <<= 1) { s += __shfl_xor(s, off); q += __shfl_xor(q, off); }
        float mu = s * (1.f / 64.f), var = q * (1.f / 64.f) - mu * mu;
        float sc = rsqrtf(var + 1e-5f) * gd1[c0 + c], sh = ed1[c0 + c] - mu * sc;
        z2[r * 64 + c0 + c] = fmaxf(fmaf(v, sc, sh), 0.f);
    }
}

// layer d2 (64 -> 32) + classifier (32 -> 10). 1 block x 256thr; wave cw = 8 cols.
__global__ __launch_bounds__(256) void tail_d2c_kernel(
    const float* __restrict__ z2, const float* __restrict__ wd2,
    const float* __restrict__ gd2, const float* __restrict__ ed2,
    const float* __restrict__ wc, const float* __restrict__ bc,
    float* __restrict__ out)
{
    __shared__ float Xq[4160];           // [64k][65]
    __shared__ float Z3t[2048];          // [32][64]
    __shared__ float WcL[320];           // [10][32]
    const int t = threadIdx.x, r = t & 63, cw = t >> 6;
    const int c03 = cw * 8;
    for (int i = t; i < 4096; i += 256) {
        int kk = i & 63, rr = i >> 6;
        Xq[kk * 65 + rr] = z2[rr * 64 + kk];
    }
    if (t < 80) ((float4*)WcL)[t] = ((const float4*)wc)[t];
    __syncthreads();
    const float4* wf4 = (const float4*)wd2;  // [32][16 float4]
    float acc[8] = {0.f,0.f,0.f,0.f,0.f,0.f,0.f,0.f};
#pragma unroll 4
    for (int k4 = 0; k4 < 16; ++k4) {
        float xv[4];
#pragma unroll
        for (int j = 0; j < 4; ++j) xv[j] = Xq[(k4 * 4 + j) * 65 + r];
#pragma unroll
        for (int c = 0; c < 8; ++c) {
            float4 w = wf4[(c03 + c) * 16 + k4];
            acc[c] = fmaf(xv[0], w.x, acc[c]);
            acc[c] = fmaf(xv[1], w.y, acc[c]);
            acc[c] = fmaf(xv[2], w.z, acc[c]);
            acc[c] = fmaf(xv[3], w.w, acc[c]);
        }
    }
#pragma unroll
    for (int c = 0; c < 8; ++c) {
        float v = acc[c];
        float s = v, q = v * v;
#pragma unroll
        for (int off = 1; off < 64; off <<= 1) { s += __shfl_xor(s, off); q += __shfl_xor(q, off); }
        float mu = s * (1.f / 64.f), var = q * (1.f / 64.f) - mu * mu;
        float sc = rsqrtf(var + 1e-5f) * gd2[c03 + c], sh = ed2[c03 + c] - mu * sc;
        Z3t[(c03 + c) * 64 + r] = fmaxf(fmaf(v, sc, sh), 0.f);
    }
    __syncthreads();
#pragma unroll
    for (int i = 0; i < 3; ++i) {
        int idx = t + i * 256;
        if (idx < 640) {
            int rr = idx / 10, c = idx - rr * 10;
            float s = bc[c];
#pragma unroll
            for (int kk = 0; kk < 32; ++kk) s = fmaf(Z3t[kk * 64 + rr], WcL[c * 32 + kk], s);
            out[idx] = s;
        }
    }
}

// ---------------- launch ----------------

extern "C" void kernel_launch(void* const* d_in, const int* in_sizes, int n_in,
                              void* d_out, int out_size, void* d_ws, size_t ws_size,
                              hipStream_t stream) {
    (void)in_sizes; (void)n_in; (void)out_size; (void)ws_size;
    const float* x  = (const float*)d_in[0];
    const int* pos  = (const int*)d_in[1];
    const float *w1 = (const float*)d_in[2],  *b1 = (const float*)d_in[3],
                *g1 = (const float*)d_in[4],  *e1 = (const float*)d_in[5];
    const float *w2 = (const float*)d_in[6],  *b2 = (const float*)d_in[7],
                *g2 = (const float*)d_in[8],  *e2 = (const float*)d_in[9];
    const float *w3 = (const float*)d_in[10], *b3 = (const float*)d_in[11],
                *g3 = (const float*)d_in[12], *e3 = (const float*)d_in[13];
    const float *ws1 = (const float*)d_in[14], *ws2 = (const float*)d_in[15];
    const float *wi = (const float*)d_in[16], *bi = (const float*)d_in[17],
                *gi = (const float*)d_in[18], *ei = (const float*)d_in[19];
    const float *wk = (const float*)d_in[20], *bk = (const float*)d_in[21];   // k before q!
    const float *wq = (const float*)d_in[22], *bq = (const float*)d_in[23];
    const float *wm = (const float*)d_in[24], *bm = (const float*)d_in[25],
                *gm = (const float*)d_in[26], *em = (const float*)d_in[27];
    const float *wd1 = (const float*)d_in[28], *bd1 = (const float*)d_in[29],
                *gd1 = (const float*)d_in[30], *ed1 = (const float*)d_in[31];
    const float *wd2 = (const float*)d_in[32], *bd2 = (const float*)d_in[33],
                *gd2 = (const float*)d_in[34], *ed2 = (const float*)d_in[35];
    const float *wc = (const float*)d_in[36], *bc = (const float*)d_in[37];
    float* out = (float*)d_out;
    (void)bm; (void)bd1; (void)bd2;   // linear biases cancel under train-mode BN

    char* w8 = (char*)d_ws;
    bf16*  actA   = (bf16*)(w8);                    // 11,960,320
    bf16*  actB   = (bf16*)(w8 + 11960320);         // 11,960,320
    bf16*  whi    = (bf16*)(w8 + 23920640);         //    278,528
    bf16*  wlo    = (bf16*)(w8 + 24199168);         //    278,528
    float* tab    = (float*)(w8 + 24477696);        //    435,200
    float* stats  = (float*)(w8 + 24912896);        //      8,192
    float* pooled = (float*)(w8 + 24921088);        //     65,536
    float* sebuf  = (float*)(w8 + 24986624);        //     65,536
    float* esum   = (float*)(w8 + 25052160);        //     65,536
    float* yvb    = (float*)(w8 + 25117696);        //     65,536
    // tail intermediates reuse regions that are dead after attn (rewritten by prep each launch)
    float* z1     = esum;        // 32,768 of 65,536 (esum last read by attn3)
    float* z2     = sebuf;       // 16,384 of 65,536 (sebuf last read by inconv gemm)

    prep_kernel<<<977, 256, 0, stream>>>(stats, pooled, esum, w2, w3, wi, whi, wlo, tab);
    // L1: 10 -> 64 -> Y1 = actB + stats1
    gemm_l1_kernel<<<365, 256, 0, stream>>>(x, w1, b1, actB, stats);
    // L2: 64 -> 128, fused BN1 -> Y2 = actA + stats2
    mfma_gemm<1, 64, 2><<<730, 256, 0, stream>>>(actB, whi, wlo, b2,
                                                 actA, 128, stats + 512, stats, g1, e1, nullptr);
    // L3: 128 -> 256, fused BN2 -> Y3 = actB + stats3
    mfma_gemm<1, 128, 4><<<1460, 256, 0, stream>>>(actA, whi + 8192, wlo + 8192, b3,
                                                   actB, 256, stats + 1024, stats + 512, g2, e2, nullptr);
    // pool (fused BN3+relu) -> pooled; SE MLP -> sebuf
    pool_partial_kernel<<<dim3(64, 8), 256, 0, stream>>>(actB, stats + 1024, g3, e3, pooled);
    se_mlp_kernel<<<64, 256, 0, stream>>>(pooled, ws1, ws2, sebuf);
    // inconv: A = Y3 with fused BN3+relu+SE-residual -> Yi = actA + statsi
    mfma_gemm<2, 256, 4><<<1460, 256, 0, stream>>>(actB, whi + 40960, wlo + 40960, bi,
                                                   actA, 256, stats + 1536, stats + 1024, g3, e3, sebuf);
    // bn_i + relu + PE -> e = actB; esum fused
    bnrelu8_kernel<<<BT * 256 / 2048, 256, 0, stream>>>(actA, stats + 1536, gi, ei, actB, tab, pos, esum);
    // attention v3: q GEMM fused away via kq = wq^T.ks
    attn3_kernel<<<dim3(64, 16), 64, 0, stream>>>(actB, esum, wk, bk, wq, bq, yvb);
    // tail v4: column-parallel, v2-proven building blocks
    tail_m_kernel<<<16, 256, 0, stream>>>(yvb, wm, gm, em, z1);
    tail_d1_kernel<<<8, 256, 0, stream>>>(z1, wd1, gd1, ed1, z2);
    tail_d2c_kernel<<<1, 256, 0, stream>>>(z2, wd2, gd2, ed2, wc, bc, out);
}